// Round 3
// baseline (5382.881 us; speedup 1.0000x reference)
//
#include <hip/hip_runtime.h>
#include <hip/hip_bf16.h>
#include <math.h>

// All I/O fp32 (per reference setup_inputs dtypes). Internal compute fp32,
// stats in fp64. NaN-safe relu everywhere: (v > 0 ? v : 0).

__device__ inline double blockReduceSumD(double v, double* sh) {
    int t = threadIdx.x;
    sh[t] = v; __syncthreads();
    for (int s = blockDim.x >> 1; s > 0; s >>= 1) {
        if (t < s) sh[t] += sh[t + s];
        __syncthreads();
    }
    double r = sh[0]; __syncthreads();
    return r;
}

// ---------- MVN: per (b,c) spatial mean/var normalize; optional centered copy ----------
__global__ __launch_bounds__(256) void mvn_k(const float* __restrict__ X,
                                             float* __restrict__ Yn,
                                             float* __restrict__ Yc, int HW) {
    __shared__ double sh[256];
    int bc = blockIdx.x;
    const float* x = X + (size_t)bc * HW;
    int t = threadIdx.x;
    float v[4];
    double s = 0.0;
    #pragma unroll
    for (int r = 0; r < 4; ++r) { v[r] = x[t + r * 256]; s += (double)v[r]; }
    double tot = blockReduceSumD(s, sh);
    double ss = 0.0;
    #pragma unroll
    for (int r = 0; r < 4; ++r) ss += (double)v[r] * (double)v[r];
    double tot2 = blockReduceSumD(ss, sh);
    double mean = tot / HW;
    double var = (tot2 - tot * tot / HW) / (HW - 1);
    float inv = (float)(1.0 / sqrt(var + 1e-5));
    float m = (float)mean;
    #pragma unroll
    for (int r = 0; r < 4; ++r) {
        size_t idx = (size_t)bc * HW + t + r * 256;
        float c = v[r] - m;
        Yn[idx] = c * inv;
        if (Yc) Yc[idx] = c;
    }
}

// ---------- generic batched conv1x1 GEMM: Y[b][o][n] = act(sum_c W[o][c]*X[b][c][n] + bias[o]) ----------
__global__ __launch_bounds__(256) void gemm_k(const float* __restrict__ W, long wbstride,
                                              const float* __restrict__ X,
                                              const float* __restrict__ bias,
                                              float* __restrict__ Y,
                                              const float* __restrict__ add_src,
                                              int C, int O, int N, int relu) {
    int bb = blockIdx.z;
    int obase = blockIdx.y * 32;
    int nbase = blockIdx.x * 32;
    const float* Wb = W + (size_t)bb * wbstride;
    const float* Xb = X + (size_t)bb * C * N;

    __shared__ float As[32][33];  // [k][o]
    __shared__ float Bs[32][33];  // [k][n]

    int t = threadIdx.x;
    int tx = t & 15, ty = t >> 4;
    float acc00 = 0, acc01 = 0, acc10 = 0, acc11 = 0;

    for (int cb = 0; cb < C; cb += 32) {
        {
            int k = t & 31, o0 = t >> 5;
            #pragma unroll
            for (int r = 0; r < 4; ++r) {
                int ol = o0 + r * 8;
                int o = obase + ol;
                float v = 0.f;
                if (o < O) v = Wb[(size_t)o * C + cb + k];
                As[k][ol] = v;
            }
            int n0 = t & 31, k0 = t >> 5;
            int n = nbase + n0;
            #pragma unroll
            for (int r = 0; r < 4; ++r) {
                int k2 = k0 + r * 8;
                float v = 0.f;
                if (n < N) v = Xb[(size_t)(cb + k2) * N + n];
                Bs[k2][n0] = v;
            }
        }
        __syncthreads();
        #pragma unroll
        for (int k = 0; k < 32; ++k) {
            float a0 = As[k][ty], a1 = As[k][ty + 16];
            float b0 = Bs[k][tx], b1 = Bs[k][tx + 16];
            acc00 += a0 * b0; acc01 += a0 * b1;
            acc10 += a1 * b0; acc11 += a1 * b1;
        }
        __syncthreads();
    }

    float accs[2][2] = {{acc00, acc01}, {acc10, acc11}};
    #pragma unroll
    for (int i = 0; i < 2; ++i) {
        int o = obase + ty + i * 16;
        if (o >= O) continue;
        float bv = bias ? bias[o] : 0.f;
        #pragma unroll
        for (int j = 0; j < 2; ++j) {
            int n = nbase + tx + j * 16;
            if (n >= N) continue;
            float v = accs[i][j] + bv;
            if (relu) v = (v > 0.f) ? v : 0.f;
            size_t idx = ((size_t)bb * O + o) * N + n;
            if (add_src) v += add_src[idx];
            Y[idx] = v;
        }
    }
}

// ---------- conv3x3 VALID implicit GEMM ----------
__global__ __launch_bounds__(256) void conv3x3_k(const float* __restrict__ X,
                                                 const float* __restrict__ W,
                                                 const float* __restrict__ bias,
                                                 float* __restrict__ Y, int Cin, int O,
                                                 int IH, int IW, int OH, int OW, int relu) {
    int bb = blockIdx.z;
    int obase = blockIdx.y * 32;
    int pbase = blockIdx.x * 32;
    int OP = OH * OW;
    const float* Xb = X + (size_t)bb * Cin * IH * IW;

    __shared__ float As[32][33];
    __shared__ float Bs[32][33];

    int t = threadIdx.x;
    int tx = t & 15, ty = t >> 4;
    float acc00 = 0, acc01 = 0, acc10 = 0, acc11 = 0;

    int n0 = t & 31;
    int p = pbase + n0;
    int py = p / OW, px = p - py * OW;
    bool pvalid = p < OP;

    for (int tap = 0; tap < 9; ++tap) {
        int ky = tap / 3, kx = tap - ky * 3;
        for (int cb = 0; cb < Cin; cb += 32) {
            {
                int k = t & 31, o0 = t >> 5;
                #pragma unroll
                for (int r = 0; r < 4; ++r) {
                    int ol = o0 + r * 8;
                    int o = obase + ol;
                    As[k][ol] = W[(size_t)o * Cin * 9 + (size_t)(cb + k) * 9 + tap];
                }
                int k0 = t >> 5;
                #pragma unroll
                for (int r = 0; r < 4; ++r) {
                    int k2 = k0 + r * 8;
                    float v = 0.f;
                    if (pvalid) v = Xb[(size_t)(cb + k2) * IH * IW + (size_t)(py + ky) * IW + (px + kx)];
                    Bs[k2][n0] = v;
                }
            }
            __syncthreads();
            #pragma unroll
            for (int k = 0; k < 32; ++k) {
                float a0 = As[k][ty], a1 = As[k][ty + 16];
                float b0 = Bs[k][tx], b1 = Bs[k][tx + 16];
                acc00 += a0 * b0; acc01 += a0 * b1;
                acc10 += a1 * b0; acc11 += a1 * b1;
            }
            __syncthreads();
        }
    }

    float accs[2][2] = {{acc00, acc01}, {acc10, acc11}};
    #pragma unroll
    for (int i = 0; i < 2; ++i) {
        int o = obase + ty + i * 16;
        float bv = bias[o];
        #pragma unroll
        for (int j = 0; j < 2; ++j) {
            int n = pbase + tx + j * 16;
            if (n >= OP) continue;
            float v = accs[i][j] + bv;
            if (relu) v = (v > 0.f) ? v : 0.f;
            Y[((size_t)bb * O + o) * OP + n] = v;
        }
    }
}

// ---------- FC_S reduction: fcs[c*B + b] = sum(g^2)/sum(g) over HW ----------
__global__ __launch_bounds__(256) void fcs_k(const float* __restrict__ g,
                                             float* __restrict__ fcs, int HW, int B, int C) {
    __shared__ double sh[256];
    int bc = blockIdx.x;
    int b = bc / C, c = bc - b * C;
    const float* x = g + (size_t)bc * HW;
    double s = 0.0, ss = 0.0;
    for (int i = threadIdx.x; i < HW; i += 256) {
        double v = (double)x[i];
        s += v; ss += v * v;
    }
    double ts = blockReduceSumD(s, sh);
    double tss = blockReduceSumD(ss, sh);
    if (threadIdx.x == 0) fcs[(size_t)c * B + b] = (float)(tss / ts);
}

// ---------- attention logits: S[b][i][j] = sum_c F[b][c][i] * G[b][c][j] ----------
__global__ __launch_bounds__(256) void attn_logits_k(const float* __restrict__ F,
                                                     const float* __restrict__ G,
                                                     float* __restrict__ S, int C, int N) {
    int bb = blockIdx.z;
    int ibase = blockIdx.y * 32;
    int jbase = blockIdx.x * 32;
    const float* Fb = F + (size_t)bb * C * N;
    const float* Gb = G + (size_t)bb * C * N;

    __shared__ float As[32][33];  // [k][i]
    __shared__ float Bs[32][33];  // [k][j]

    int t = threadIdx.x;
    int tx = t & 15, ty = t >> 4;
    float acc00 = 0, acc01 = 0, acc10 = 0, acc11 = 0;

    for (int cb = 0; cb < C; cb += 32) {
        int m0 = t & 31, k0 = t >> 5;
        #pragma unroll
        for (int r = 0; r < 4; ++r) {
            int k2 = k0 + r * 8;
            As[k2][m0] = Fb[(size_t)(cb + k2) * N + ibase + m0];
            Bs[k2][m0] = Gb[(size_t)(cb + k2) * N + jbase + m0];
        }
        __syncthreads();
        #pragma unroll
        for (int k = 0; k < 32; ++k) {
            float a0 = As[k][ty], a1 = As[k][ty + 16];
            float b0 = Bs[k][tx], b1 = Bs[k][tx + 16];
            acc00 += a0 * b0; acc01 += a0 * b1;
            acc10 += a1 * b0; acc11 += a1 * b1;
        }
        __syncthreads();
    }
    float accs[2][2] = {{acc00, acc01}, {acc10, acc11}};
    #pragma unroll
    for (int i = 0; i < 2; ++i) {
        int ii = ibase + ty + i * 16;
        #pragma unroll
        for (int j = 0; j < 2; ++j) {
            int jj = jbase + tx + j * 16;
            S[((size_t)bb * N + ii) * N + jj] = accs[i][j];
        }
    }
}

// ---------- row softmax over last dim (N=1024) ----------
__global__ __launch_bounds__(256) void softmax_k(float* __restrict__ S) {
    __shared__ float sh[256];
    size_t row = blockIdx.x;
    float* r = S + row * 1024;
    int t = threadIdx.x;
    float v[4];
    float m = -INFINITY;
    #pragma unroll
    for (int i = 0; i < 4; ++i) { v[i] = r[t + i * 256]; m = fmaxf(m, v[i]); }
    sh[t] = m; __syncthreads();
    for (int s = 128; s > 0; s >>= 1) { if (t < s) sh[t] = fmaxf(sh[t], sh[t + s]); __syncthreads(); }
    m = sh[0]; __syncthreads();
    float sum = 0;
    #pragma unroll
    for (int i = 0; i < 4; ++i) { v[i] = expf(v[i] - m); sum += v[i]; }
    sh[t] = sum; __syncthreads();
    for (int s = 128; s > 0; s >>= 1) { if (t < s) sh[t] += sh[t + s]; __syncthreads(); }
    float inv = 1.f / sh[0]; __syncthreads();
    #pragma unroll
    for (int i = 0; i < 4; ++i) r[t + i * 256] = v[i] * inv;
}

// ---------- attention apply: out[b][c][i] = sum_j H[b][c][j] * S[b][i][j] ----------
__global__ __launch_bounds__(256) void attn_apply_k(const float* __restrict__ Hs,
                                                    const float* __restrict__ S,
                                                    float* __restrict__ outp, int C, int N) {
    int bb = blockIdx.z;
    int cbase = blockIdx.y * 32;
    int ibase = blockIdx.x * 32;
    const float* Hb = Hs + (size_t)bb * C * N;
    const float* Sb = S + (size_t)bb * N * N;

    __shared__ float As[32][33];  // [k(j)][c]
    __shared__ float Bs[32][33];  // [k(j)][i]

    int t = threadIdx.x;
    int tx = t & 15, ty = t >> 4;
    float acc00 = 0, acc01 = 0, acc10 = 0, acc11 = 0;

    for (int jb = 0; jb < N; jb += 32) {
        int k0 = t & 31, m0 = t >> 5;
        #pragma unroll
        for (int r = 0; r < 4; ++r) {
            int ml = m0 + r * 8;
            As[k0][ml] = Hb[(size_t)(cbase + ml) * N + jb + k0];
            Bs[k0][ml] = Sb[(size_t)(ibase + ml) * N + jb + k0];
        }
        __syncthreads();
        #pragma unroll
        for (int k = 0; k < 32; ++k) {
            float a0 = As[k][ty], a1 = As[k][ty + 16];
            float b0 = Bs[k][tx], b1 = Bs[k][tx + 16];
            acc00 += a0 * b0; acc01 += a0 * b1;
            acc10 += a1 * b0; acc11 += a1 * b1;
        }
        __syncthreads();
    }
    float accs[2][2] = {{acc00, acc01}, {acc10, acc11}};
    #pragma unroll
    for (int i = 0; i < 2; ++i) {
        int c = cbase + ty + i * 16;
        #pragma unroll
        for (int j = 0; j < 2; ++j) {
            int ii = ibase + tx + j * 16;
            outp[((size_t)bb * C + c) * N + ii] = accs[i][j];
        }
    }
}

// ---------- covariance: cov[b][c][d] = sum_i fs[b,c,i]*fs[b,d,i] / M ----------
__global__ __launch_bounds__(1024) void cov_k(const float* __restrict__ fs,
                                              float* __restrict__ cov, int Cd, int M) {
    int bb = blockIdx.x;
    int t = threadIdx.x;
    int c = t >> 5, d = t & 31;
    const float* p = fs + (size_t)bb * Cd * M;
    float s = 0;
    for (int i = 0; i < M; ++i) s += p[(size_t)c * M + i] * p[(size_t)d * M + i];
    cov[((size_t)bb * Cd + c) * Cd + d] = s / M;
}

// ---------- fused epilogue: p = cbrt(relu(part1*part2*part3)) ----------
__global__ __launch_bounds__(256) void fuse_k(const float* __restrict__ ffc,
                                              const float* __restrict__ fc2t,
                                              const float* __restrict__ p2,
                                              const float* __restrict__ p3,
                                              float* __restrict__ out, int B, int C, int N) {
    size_t idx = (size_t)blockIdx.x * 256 + threadIdx.x;
    size_t total = (size_t)B * C * N;
    if (idx >= total) return;
    int c = (int)((idx / N) % C);
    int b = (int)(idx / ((size_t)N * C));
    float part1 = ffc[idx] * fc2t[(size_t)c * B + b];
    float v = part1 * p2[idx] * p3[idx];
    v = (v > 0.f) ? v : 0.f;   // NaN-safe relu
    out[idx] = cbrtf(v);
}

// ---------- launch ----------
extern "C" void kernel_launch(void* const* d_in, const int* in_sizes, int n_in,
                              void* d_out, int out_size, void* d_ws, size_t ws_size,
                              hipStream_t stream) {
    typedef const float* fp;
    fp content = (fp)d_in[0];
    fp style   = (fp)d_in[1];
    fp wf_san = (fp)d_in[2],  bf_san = (fp)d_in[3];
    fp wg_san = (fp)d_in[4],  bg_san = (fp)d_in[5];
    fp wh_san = (fp)d_in[6],  bh_san = (fp)d_in[7];
    fp wf_mcc = (fp)d_in[8],  bf_mcc = (fp)d_in[9];
    fp wg_mcc = (fp)d_in[10], bg_mcc = (fp)d_in[11];
    fp w_fc   = (fp)d_in[12], b_fc   = (fp)d_in[13];
    fp w_out  = (fp)d_in[14], b_out  = (fp)d_in[15];
    fp wc1 = (fp)d_in[16], bc1 = (fp)d_in[17];
    fp wc2 = (fp)d_in[18], bc2 = (fp)d_in[19];
    fp wc3 = (fp)d_in[20], bc3 = (fp)d_in[21];
    fp ws1 = (fp)d_in[22], bs1 = (fp)d_in[23];
    fp ws2 = (fp)d_in[24], bs2 = (fp)d_in[25];
    fp ws3 = (fp)d_in[26], bs3 = (fp)d_in[27];
    fp w_unc = (fp)d_in[28], b_unc = (fp)d_in[29];

    const int B = 16, C = 512, HW = 1024;
    const size_t NE = (size_t)B * C * HW;  // 8388608 elements

    // fp32 slots (NE floats = 33.55 MB each), 7 slots + smalls = ~241 MB
    float* ws = (float*)d_ws;
    float* cn   = ws;             // A: cn,  dead after step 16  -> S low half
    float* sn   = ws + NE;        // B: sn,  dead after step 17  -> S high half
    float* fs0  = ws + 2 * NE;    // C: fs0 (dead after conv1)   -> part2
    float* ffc  = ws + 3 * NE;    // D: ffc                      -> p (in place)
    float* E    = ws + 4 * NE;    // E: g -> t1+t2 -> s1+s2      -> Fsb
    float* Gsb  = ws + 5 * NE;    // F: Gsb (dead after logits)  -> part3
    float* Hsb  = ws + 6 * NE;    // G: Hsb
    float* Sbuf = ws;             // 2*NE floats overlay on A+B

    float* small = ws + 7 * NE;
    float* fc_c  = small;                     // 16*32*1024 = 524288
    float* fs_c  = fc_c + 524288;             // 16*32*784  = 401408
    float* out32 = fs_c + 401408;             // 16*32*1024 = 524288
    float* fcs   = out32 + 524288;            // 512*16
    float* fc2t  = fcs + 8192;                // 512*16
    float* cov   = fc2t + 8192;               // 16*32*32

    float* gbuf = E;
    float* t1 = E;                  // 16*256*1024 = 4194304
    float* t2 = E + 4194304;        // 16*128*1024 = 2097152
    float* s1 = E;                  // 16*256*900  = 3686400
    float* s2 = E + 4194304;        // 16*128*784  = 1254912
    float* Fsb = E;                 // E reuse after fs-chain
    float* part3 = Gsb;             // F reuse after logits
    float* part2 = fs0;             // C reuse after conv chain starts
    float* pbuf = ffc;              // D in-place

    // 1-2: MVN
    mvn_k<<<B * C, 256, 0, stream>>>(content, cn, nullptr, HW);
    mvn_k<<<B * C, 256, 0, stream>>>(style, sn, fs0, HW);

    // 3: F_Fc = conv1x1(cn, wf_mcc)
    gemm_k<<<dim3(32, 16, 16), 256, 0, stream>>>(wf_mcc, 0, cn, bf_mcc, ffc, nullptr, 512, 512, 1024, 0);
    // 4: g = conv1x1(sn, wg_mcc)
    gemm_k<<<dim3(32, 16, 16), 256, 0, stream>>>(wg_mcc, 0, sn, bg_mcc, gbuf, nullptr, 512, 512, 1024, 0);
    // 5: FC_S = sum(g^2)/sum(g)   (stored transposed [c][b])
    fcs_k<<<B * C, 256, 0, stream>>>(gbuf, fcs, HW, B, C);
    // 6: FC_S @ w_fc.T + b_fc  -> fc2t [o][b]
    gemm_k<<<dim3(1, 16, 1), 256, 0, stream>>>(w_fc, 0, fcs, b_fc, fc2t, nullptr, 512, 512, 16, 0);

    // 7-9: fc_ chain on cn
    gemm_k<<<dim3(32, 8, 16), 256, 0, stream>>>(wc1, 0, cn, bc1, t1, nullptr, 512, 256, 1024, 1);
    gemm_k<<<dim3(32, 4, 16), 256, 0, stream>>>(wc2, 0, t1, bc2, t2, nullptr, 256, 128, 1024, 1);
    gemm_k<<<dim3(32, 1, 16), 256, 0, stream>>>(wc3, 0, t2, bc3, fc_c, nullptr, 128, 32, 1024, 0);

    // 10-12: fs_ chain on fs0 (centered style)
    conv3x3_k<<<dim3(29, 8, 16), 256, 0, stream>>>(fs0, ws1, bs1, s1, 512, 256, 32, 32, 30, 30, 1);
    conv3x3_k<<<dim3(25, 4, 16), 256, 0, stream>>>(s1, ws2, bs2, s2, 256, 128, 30, 30, 28, 28, 1);
    gemm_k<<<dim3(25, 1, 16), 256, 0, stream>>>(ws3, 0, s2, bs3, fs_c, nullptr, 128, 32, 784, 0);

    // 13: cov
    cov_k<<<B, 1024, 0, stream>>>(fs_c, cov, 32, 784);
    // 14: out32 = cov @ fc_
    gemm_k<<<dim3(32, 1, 16), 256, 0, stream>>>(cov, 1024, fc_c, nullptr, out32, nullptr, 32, 32, 1024, 0);
    // 15: part2 = conv1x1(out32, w_unc, b_unc)  (into slot C, fs0 dead)
    gemm_k<<<dim3(32, 16, 16), 256, 0, stream>>>(w_unc, 0, out32, b_unc, part2, nullptr, 32, 512, 1024, 0);

    // 16-17: SANet F/G projections (last uses of cn, sn)
    gemm_k<<<dim3(32, 16, 16), 256, 0, stream>>>(wf_san, 0, cn, bf_san, Fsb, nullptr, 512, 512, 1024, 0);
    gemm_k<<<dim3(32, 16, 16), 256, 0, stream>>>(wg_san, 0, sn, bg_san, Gsb, nullptr, 512, 512, 1024, 0);

    // 18-19: logits (S overlays A+B, both dead now), softmax
    attn_logits_k<<<dim3(32, 32, 16), 256, 0, stream>>>(Fsb, Gsb, Sbuf, 512, 1024);
    softmax_k<<<B * HW, 256, 0, stream>>>(Sbuf);

    // 20: H projection (own slot G)
    gemm_k<<<dim3(32, 16, 16), 256, 0, stream>>>(wh_san, 0, style, bh_san, Hsb, nullptr, 512, 512, 1024, 0);

    // 21: part3 = H @ S^T  into slot F (Gsb dead)
    attn_apply_k<<<dim3(32, 16, 16), 256, 0, stream>>>(Hsb, Sbuf, part3, 512, 1024);

    // 22: p = cbrt(relu(part1*part2*part3))  (in-place over ffc)
    fuse_k<<<(unsigned)((NE + 255) / 256), 256, 0, stream>>>(ffc, fc2t, part2, part3, pbuf, B, C, HW);

    // 23: out = conv1x1(p, w_out, b_out) + content
    gemm_k<<<dim3(32, 16, 16), 256, 0, stream>>>(w_out, 0, pbuf, b_out, (float*)d_out, content, 512, 512, 1024, 0);
}

// Round 4
// 2914.485 us; speedup vs baseline: 1.8469x; 1.8469x over previous
//
#include <hip/hip_runtime.h>
#include <hip/hip_bf16.h>
#include <math.h>

// fp32 everywhere (matches reference dtypes). Heavy ops: 64x64-tile GEMM with
// 4x4 microtile; conv3x3 as LDS-patch implicit GEMM with pre-reordered weights.

__device__ inline double blockReduceSumD(double v, double* sh) {
    int t = threadIdx.x;
    sh[t] = v; __syncthreads();
    for (int s = blockDim.x >> 1; s > 0; s >>= 1) {
        if (t < s) sh[t] += sh[t + s];
        __syncthreads();
    }
    double r = sh[0]; __syncthreads();
    return r;
}

__device__ inline float4 ld4_guard(const float* __restrict__ row, int n, int N) {
    if (n + 3 < N) return *(const float4*)(row + n);
    float4 v = make_float4(0.f, 0.f, 0.f, 0.f);
    if (n < N) v.x = row[n];
    if (n + 1 < N) v.y = row[n + 1];
    if (n + 2 < N) v.z = row[n + 2];
    if (n + 3 < N) v.w = row[n + 3];
    return v;
}

// ---------- MVN ----------
__global__ __launch_bounds__(256) void mvn_k(const float* __restrict__ X,
                                             float* __restrict__ Yn,
                                             float* __restrict__ Yc, int HW) {
    __shared__ double sh[256];
    int bc = blockIdx.x;
    const float* x = X + (size_t)bc * HW;
    int t = threadIdx.x;
    float v[4];
    double s = 0.0;
    #pragma unroll
    for (int r = 0; r < 4; ++r) { v[r] = x[t + r * 256]; s += (double)v[r]; }
    double tot = blockReduceSumD(s, sh);
    double ss = 0.0;
    #pragma unroll
    for (int r = 0; r < 4; ++r) ss += (double)v[r] * (double)v[r];
    double tot2 = blockReduceSumD(ss, sh);
    double mean = tot / HW;
    double var = (tot2 - tot * tot / HW) / (HW - 1);
    float inv = (float)(1.0 / sqrt(var + 1e-5));
    float m = (float)mean;
    #pragma unroll
    for (int r = 0; r < 4; ++r) {
        size_t idx = (size_t)bc * HW + t + r * 256;
        float c = v[r] - m;
        Yn[idx] = c * inv;
        if (Yc) Yc[idx] = c;
    }
}

// ---------- 64x64-tile GEMM, 4x4 microtile ----------
// Y[b][m][n] = act( sum_k A[k][m] * B[k][n] + bias[m] ) (+ add_src)
// TA=0: A from P[m*lda + k] (k-contig, e.g. weights W[o][c])
// TA=1: A from P[k*lda + m] (m-contig, e.g. F[c][i] for logits)
// TB=0: B from Q[k*ldb + n] (n-contig, e.g. X[c][n])
// TB=1: B from Q[n*ldb + k] (k-contig, e.g. S[i][j] for apply)
template <int TA, int TB>
__global__ __launch_bounds__(256) void g64_k(const float* __restrict__ P, long pstride, int lda,
                                             const float* __restrict__ Q, long qstride, int ldb,
                                             const float* __restrict__ bias,
                                             float* __restrict__ Y,
                                             const float* __restrict__ add_src,
                                             int K, int M, int N, int relu) {
    int bb = blockIdx.z;
    int mbase = blockIdx.y * 64;
    int nbase = blockIdx.x * 64;
    const float* Pb = P + (size_t)bb * pstride;
    const float* Qb = Q + (size_t)bb * qstride;

    __shared__ float As[16][68];  // [k][m]
    __shared__ float Bs[16][68];  // [k][n]

    int t = threadIdx.x;
    int tx = t & 15, ty = t >> 4;
    float acc[4][4] = {{0.f, 0.f, 0.f, 0.f}, {0.f, 0.f, 0.f, 0.f},
                       {0.f, 0.f, 0.f, 0.f}, {0.f, 0.f, 0.f, 0.f}};

    for (int cb = 0; cb < K; cb += 16) {
        if (TA == 0) {
            int mm = t >> 2;            // 0..63
            int k4 = (t & 3) * 4;       // 0,4,8,12
            int m = mbase + mm;
            float4 a = (m < M) ? *(const float4*)&Pb[(size_t)m * lda + cb + k4]
                               : make_float4(0.f, 0.f, 0.f, 0.f);
            As[k4 + 0][mm] = a.x; As[k4 + 1][mm] = a.y;
            As[k4 + 2][mm] = a.z; As[k4 + 3][mm] = a.w;
        } else {
            int k = t >> 4;             // 0..15
            int m4 = (t & 15) * 4;
            float4 a = ld4_guard(&Pb[(size_t)(cb + k) * lda], mbase + m4, M);
            *(float4*)&As[k][m4] = a;
        }
        if (TB == 0) {
            int k = t >> 4;
            int n4 = (t & 15) * 4;
            float4 b = ld4_guard(&Qb[(size_t)(cb + k) * ldb], nbase + n4, N);
            *(float4*)&Bs[k][n4] = b;
        } else {
            int nn = t >> 2;
            int k4 = (t & 3) * 4;
            int n = nbase + nn;
            float4 b = (n < N) ? *(const float4*)&Qb[(size_t)n * ldb + cb + k4]
                               : make_float4(0.f, 0.f, 0.f, 0.f);
            Bs[k4 + 0][nn] = b.x; Bs[k4 + 1][nn] = b.y;
            Bs[k4 + 2][nn] = b.z; Bs[k4 + 3][nn] = b.w;
        }
        __syncthreads();
        #pragma unroll
        for (int k = 0; k < 16; ++k) {
            float4 a = *(const float4*)&As[k][ty * 4];
            float4 b = *(const float4*)&Bs[k][tx * 4];
            acc[0][0] += a.x * b.x; acc[0][1] += a.x * b.y; acc[0][2] += a.x * b.z; acc[0][3] += a.x * b.w;
            acc[1][0] += a.y * b.x; acc[1][1] += a.y * b.y; acc[1][2] += a.y * b.z; acc[1][3] += a.y * b.w;
            acc[2][0] += a.z * b.x; acc[2][1] += a.z * b.y; acc[2][2] += a.z * b.z; acc[2][3] += a.z * b.w;
            acc[3][0] += a.w * b.x; acc[3][1] += a.w * b.y; acc[3][2] += a.w * b.z; acc[3][3] += a.w * b.w;
        }
        __syncthreads();
    }

    #pragma unroll
    for (int i = 0; i < 4; ++i) {
        int m = mbase + ty * 4 + i;
        if (m >= M) continue;
        float bv = bias ? bias[m] : 0.f;
        size_t rowoff = ((size_t)bb * M + m) * N;
        int n0 = nbase + tx * 4;
        float v[4];
        #pragma unroll
        for (int j = 0; j < 4; ++j) {
            float x = acc[i][j] + bv;
            if (relu) x = (x > 0.f) ? x : 0.f;
            v[j] = x;
        }
        if (n0 + 3 < N) {
            float4 o4 = make_float4(v[0], v[1], v[2], v[3]);
            if (add_src) {
                float4 a4 = *(const float4*)&add_src[rowoff + n0];
                o4.x += a4.x; o4.y += a4.y; o4.z += a4.z; o4.w += a4.w;
            }
            *(float4*)&Y[rowoff + n0] = o4;
        } else {
            #pragma unroll
            for (int j = 0; j < 4; ++j) {
                int n = n0 + j;
                if (n < N) {
                    float x = v[j];
                    if (add_src) x += add_src[rowoff + n];
                    Y[rowoff + n] = x;
                }
            }
        }
    }
}

// ---------- legacy 32x32 GEMM (kept for tiny-N: w_fc with N=16) ----------
__global__ __launch_bounds__(256) void gemm_k(const float* __restrict__ W, long wbstride,
                                              const float* __restrict__ X,
                                              const float* __restrict__ bias,
                                              float* __restrict__ Y,
                                              const float* __restrict__ add_src,
                                              int C, int O, int N, int relu) {
    int bb = blockIdx.z;
    int obase = blockIdx.y * 32;
    int nbase = blockIdx.x * 32;
    const float* Wb = W + (size_t)bb * wbstride;
    const float* Xb = X + (size_t)bb * C * N;

    __shared__ float As[32][33];
    __shared__ float Bs[32][33];

    int t = threadIdx.x;
    int tx = t & 15, ty = t >> 4;
    float acc00 = 0, acc01 = 0, acc10 = 0, acc11 = 0;

    for (int cb = 0; cb < C; cb += 32) {
        {
            int k = t & 31, o0 = t >> 5;
            #pragma unroll
            for (int r = 0; r < 4; ++r) {
                int ol = o0 + r * 8;
                int o = obase + ol;
                float v = 0.f;
                if (o < O) v = Wb[(size_t)o * C + cb + k];
                As[k][ol] = v;
            }
            int n0 = t & 31, k0 = t >> 5;
            int n = nbase + n0;
            #pragma unroll
            for (int r = 0; r < 4; ++r) {
                int k2 = k0 + r * 8;
                float v = 0.f;
                if (n < N) v = Xb[(size_t)(cb + k2) * N + n];
                Bs[k2][n0] = v;
            }
        }
        __syncthreads();
        #pragma unroll
        for (int k = 0; k < 32; ++k) {
            float a0 = As[k][ty], a1 = As[k][ty + 16];
            float b0 = Bs[k][tx], b1 = Bs[k][tx + 16];
            acc00 += a0 * b0; acc01 += a0 * b1;
            acc10 += a1 * b0; acc11 += a1 * b1;
        }
        __syncthreads();
    }

    float accs[2][2] = {{acc00, acc01}, {acc10, acc11}};
    #pragma unroll
    for (int i = 0; i < 2; ++i) {
        int o = obase + ty + i * 16;
        if (o >= O) continue;
        float bv = bias ? bias[o] : 0.f;
        #pragma unroll
        for (int j = 0; j < 2; ++j) {
            int n = nbase + tx + j * 16;
            if (n >= N) continue;
            float v = accs[i][j] + bv;
            if (relu) v = (v > 0.f) ? v : 0.f;
            size_t idx = ((size_t)bb * O + o) * N + n;
            if (add_src) v += add_src[idx];
            Y[idx] = v;
        }
    }
}

// ---------- conv3x3 weight reorder: Wt[tap][c][o] = W[o][c][tap] ----------
__global__ __launch_bounds__(256) void reorder_w3_k(const float* __restrict__ W,
                                                    float* __restrict__ Wt,
                                                    int O, int Cin) {
    int idx = blockIdx.x * 256 + threadIdx.x;
    int total = O * Cin * 9;
    if (idx >= total) return;
    int tap = idx / (Cin * O);
    int rem = idx - tap * (Cin * O);
    int c = rem / O;
    int o = rem - c * O;
    Wt[idx] = W[((size_t)o * Cin + c) * 9 + tap];
}

// ---------- conv3x3 VALID, LDS-patch implicit GEMM ----------
// Block: 64 out-channels x (2 rows x 32 cols) of output. KC=16 channels/iter.
// Patch (16ch x 4rows x 32cols) loaded once per c-block, reused by all 9 taps.
__global__ __launch_bounds__(256) void conv3x3_k(const float* __restrict__ X,
                                                 const float* __restrict__ Wt,
                                                 const float* __restrict__ bias,
                                                 float* __restrict__ Y, int Cin, int O,
                                                 int IH, int IW, int OH, int OW, int relu) {
    int bb = blockIdx.z;
    int obase = blockIdx.y * 64;
    int pybase = blockIdx.x * 2;
    const float* Xb = X + (size_t)bb * Cin * IH * IW;

    __shared__ float patch[16 * 4 * 32];   // [c][row][col]
    __shared__ float Ws[9][16][68];        // [tap][c][o]

    int t = threadIdx.x;
    int tx = t & 15, ty = t >> 4;
    int r0 = (tx >= 8) ? 1 : 0;           // output row within tile
    int xb = (tx * 4) & 31;               // output col base
    float acc[4][4] = {{0.f, 0.f, 0.f, 0.f}, {0.f, 0.f, 0.f, 0.f},
                       {0.f, 0.f, 0.f, 0.f}, {0.f, 0.f, 0.f, 0.f}};

    for (int cb = 0; cb < Cin; cb += 16) {
        __syncthreads();   // previous iter's LDS reads done
        if (IW == 32) {
            #pragma unroll
            for (int e = 0; e < 2; ++e) {
                int lin = t * 8 + e * 4;           // 0..2044 step 4
                int c = lin >> 7, r = (lin >> 5) & 3, x = lin & 31;
                float4 v = *(const float4*)&Xb[(size_t)(cb + c) * 1024 + (size_t)(pybase + r) * 32 + x];
                *(float4*)&patch[lin] = v;
            }
        } else {
            #pragma unroll
            for (int e = 0; e < 8; ++e) {
                int lin = t + e * 256;
                int c = lin >> 7, r = (lin >> 5) & 3, x = lin & 31;
                float v = 0.f;
                if (x < IW) v = Xb[(size_t)(cb + c) * IH * IW + (size_t)(pybase + r) * IW + x];
                patch[lin] = v;
            }
        }
        {
            int c = t >> 4, o4 = (t & 15) * 4;
            #pragma unroll
            for (int tap = 0; tap < 9; ++tap) {
                float4 w = *(const float4*)&Wt[((size_t)tap * Cin + cb + c) * O + obase + o4];
                *(float4*)&Ws[tap][c][o4] = w;
            }
        }
        __syncthreads();

        for (int tap = 0; tap < 9; ++tap) {
            int ky = tap / 3;
            int kx = tap - ky * 3;
            int pb = (r0 + ky) * 32 + xb + kx;
            #pragma unroll
            for (int k = 0; k < 16; ++k) {
                float4 a = *(const float4*)&Ws[tap][k][ty * 4];
                int base = k * 128 + pb;
                float b0 = patch[base + 0];
                float b1 = patch[base + 1];
                float b2 = patch[base + 2];
                float b3 = patch[base + 3];
                acc[0][0] += a.x * b0; acc[0][1] += a.x * b1; acc[0][2] += a.x * b2; acc[0][3] += a.x * b3;
                acc[1][0] += a.y * b0; acc[1][1] += a.y * b1; acc[1][2] += a.y * b2; acc[1][3] += a.y * b3;
                acc[2][0] += a.z * b0; acc[2][1] += a.z * b1; acc[2][2] += a.z * b2; acc[2][3] += a.z * b3;
                acc[3][0] += a.w * b0; acc[3][1] += a.w * b1; acc[3][2] += a.w * b2; acc[3][3] += a.w * b3;
            }
        }
    }

    int py = pybase + r0;
    #pragma unroll
    for (int i = 0; i < 4; ++i) {
        int o = obase + ty * 4 + i;
        if (o >= O) continue;
        float bv = bias[o];
        size_t rowoff = ((size_t)bb * O + o) * (size_t)(OH * OW) + (size_t)py * OW;
        #pragma unroll
        for (int j = 0; j < 4; ++j) {
            int px = xb + j;
            if (px < OW) {
                float v = acc[i][j] + bv;
                if (relu) v = (v > 0.f) ? v : 0.f;
                Y[rowoff + px] = v;
            }
        }
    }
}

// ---------- FC_S reduction ----------
__global__ __launch_bounds__(256) void fcs_k(const float* __restrict__ g,
                                             float* __restrict__ fcs, int HW, int B, int C) {
    __shared__ double sh[256];
    int bc = blockIdx.x;
    int b = bc / C, c = bc - b * C;
    const float* x = g + (size_t)bc * HW;
    double s = 0.0, ss = 0.0;
    for (int i = threadIdx.x; i < HW; i += 256) {
        double v = (double)x[i];
        s += v; ss += v * v;
    }
    double ts = blockReduceSumD(s, sh);
    double tss = blockReduceSumD(ss, sh);
    if (threadIdx.x == 0) fcs[(size_t)c * B + b] = (float)(tss / ts);
}

// ---------- row softmax over last dim (N=1024) ----------
__global__ __launch_bounds__(256) void softmax_k(float* __restrict__ S) {
    __shared__ float sh[256];
    size_t row = blockIdx.x;
    float* r = S + row * 1024;
    int t = threadIdx.x;
    float v[4];
    float m = -INFINITY;
    #pragma unroll
    for (int i = 0; i < 4; ++i) { v[i] = r[t + i * 256]; m = fmaxf(m, v[i]); }
    sh[t] = m; __syncthreads();
    for (int s = 128; s > 0; s >>= 1) { if (t < s) sh[t] = fmaxf(sh[t], sh[t + s]); __syncthreads(); }
    m = sh[0]; __syncthreads();
    float sum = 0;
    #pragma unroll
    for (int i = 0; i < 4; ++i) { v[i] = expf(v[i] - m); sum += v[i]; }
    sh[t] = sum; __syncthreads();
    for (int s = 128; s > 0; s >>= 1) { if (t < s) sh[t] += sh[t + s]; __syncthreads(); }
    float inv = 1.f / sh[0]; __syncthreads();
    #pragma unroll
    for (int i = 0; i < 4; ++i) r[t + i * 256] = v[i] * inv;
}

// ---------- covariance ----------
__global__ __launch_bounds__(1024) void cov_k(const float* __restrict__ fs,
                                              float* __restrict__ cov, int Cd, int M) {
    int bb = blockIdx.x;
    int t = threadIdx.x;
    int c = t >> 5, d = t & 31;
    const float* p = fs + (size_t)bb * Cd * M;
    float s = 0;
    for (int i = 0; i < M; ++i) s += p[(size_t)c * M + i] * p[(size_t)d * M + i];
    cov[((size_t)bb * Cd + c) * Cd + d] = s / M;
}

// ---------- fused epilogue ----------
__global__ __launch_bounds__(256) void fuse_k(const float* __restrict__ ffc,
                                              const float* __restrict__ fc2t,
                                              const float* __restrict__ p2,
                                              const float* __restrict__ p3,
                                              float* __restrict__ out, int B, int C, int N) {
    size_t idx = (size_t)blockIdx.x * 256 + threadIdx.x;
    size_t total = (size_t)B * C * N;
    if (idx >= total) return;
    int c = (int)((idx / N) % C);
    int b = (int)(idx / ((size_t)N * C));
    float part1 = ffc[idx] * fc2t[(size_t)c * B + b];
    float v = part1 * p2[idx] * p3[idx];
    v = (v > 0.f) ? v : 0.f;
    out[idx] = cbrtf(v);
}

// ---------- launch ----------
extern "C" void kernel_launch(void* const* d_in, const int* in_sizes, int n_in,
                              void* d_out, int out_size, void* d_ws, size_t ws_size,
                              hipStream_t stream) {
    typedef const float* fp;
    fp content = (fp)d_in[0];
    fp style   = (fp)d_in[1];
    fp wf_san = (fp)d_in[2],  bf_san = (fp)d_in[3];
    fp wg_san = (fp)d_in[4],  bg_san = (fp)d_in[5];
    fp wh_san = (fp)d_in[6],  bh_san = (fp)d_in[7];
    fp wf_mcc = (fp)d_in[8],  bf_mcc = (fp)d_in[9];
    fp wg_mcc = (fp)d_in[10], bg_mcc = (fp)d_in[11];
    fp w_fc   = (fp)d_in[12], b_fc   = (fp)d_in[13];
    fp w_out  = (fp)d_in[14], b_out  = (fp)d_in[15];
    fp wc1 = (fp)d_in[16], bc1 = (fp)d_in[17];
    fp wc2 = (fp)d_in[18], bc2 = (fp)d_in[19];
    fp wc3 = (fp)d_in[20], bc3 = (fp)d_in[21];
    fp ws1 = (fp)d_in[22], bs1 = (fp)d_in[23];
    fp ws2 = (fp)d_in[24], bs2 = (fp)d_in[25];
    fp ws3 = (fp)d_in[26], bs3 = (fp)d_in[27];
    fp w_unc = (fp)d_in[28], b_unc = (fp)d_in[29];

    const int B = 16, C = 512, HW = 1024;
    const size_t NE = (size_t)B * C * HW;  // 8388608

    float* ws = (float*)d_ws;
    float* cn   = ws;             // A: cn  -> S low half
    float* sn   = ws + NE;        // B: sn  -> S high half
    float* fs0  = ws + 2 * NE;    // C: fs0 -> part2
    float* ffc  = ws + 3 * NE;    // D: ffc -> p (in place)
    float* E    = ws + 4 * NE;    // E: g -> t1+t2 -> s1+s2 -> Fsb
    float* Gsb  = ws + 5 * NE;    // F: Gsb -> part3
    float* Hsb  = ws + 6 * NE;    // G: Wt1+Wt2 (early) -> Hsb (late)
    float* Sbuf = ws;             // 2*NE overlay on A+B

    float* small = ws + 7 * NE;
    float* fc_c  = small;                     // 16*32*1024
    float* fs_c  = fc_c + 524288;             // 16*32*784
    float* out32 = fs_c + 401408;             // 16*32*1024
    float* fcs   = out32 + 524288;            // 512*16
    float* fc2t  = fcs + 8192;                // 512*16
    float* cov   = fc2t + 8192;               // 16*32*32

    float* gbuf = E;
    float* t1 = E;                  // 16*256*1024
    float* t2 = E + 4194304;        // 16*128*1024
    float* s1 = E;                  // 16*256*900
    float* s2 = E + 4194304;        // 16*128*784
    float* Fsb = E;                 // E reuse after fs-chain
    float* part3 = Gsb;
    float* part2 = fs0;
    float* pbuf = ffc;
    float* Wt1 = Hsb;               // 256*512*9 = 1179648 floats (G slot, dead until step 20)
    float* Wt2 = Hsb + 1179648;     // 128*256*9 = 294912 floats

    // 0: reorder conv3x3 weights into [tap][c][o]
    reorder_w3_k<<<(1179648 + 255) / 256, 256, 0, stream>>>(ws1, Wt1, 256, 512);
    reorder_w3_k<<<(294912 + 255) / 256, 256, 0, stream>>>(ws2, Wt2, 128, 256);

    // 1-2: MVN
    mvn_k<<<B * C, 256, 0, stream>>>(content, cn, nullptr, HW);
    mvn_k<<<B * C, 256, 0, stream>>>(style, sn, fs0, HW);

    // 3: F_Fc = conv1x1(cn, wf_mcc)
    g64_k<0, 0><<<dim3(16, 8, 16), 256, 0, stream>>>(wf_mcc, 0, 512, cn, (long)C * HW, HW,
                                                     bf_mcc, ffc, nullptr, 512, 512, 1024, 0);
    // 4: g = conv1x1(sn, wg_mcc)
    g64_k<0, 0><<<dim3(16, 8, 16), 256, 0, stream>>>(wg_mcc, 0, 512, sn, (long)C * HW, HW,
                                                     bg_mcc, gbuf, nullptr, 512, 512, 1024, 0);
    // 5: FC_S = sum(g^2)/sum(g)   (stored transposed [c][b])
    fcs_k<<<B * C, 256, 0, stream>>>(gbuf, fcs, HW, B, C);
    // 6: FC_S @ w_fc.T + b_fc  -> fc2t [o][b]   (N=16: legacy 32-tile)
    gemm_k<<<dim3(1, 16, 1), 256, 0, stream>>>(w_fc, 0, fcs, b_fc, fc2t, nullptr, 512, 512, 16, 0);

    // 7-9: fc_ chain on cn
    g64_k<0, 0><<<dim3(16, 4, 16), 256, 0, stream>>>(wc1, 0, 512, cn, (long)512 * 1024, 1024,
                                                     bc1, t1, nullptr, 512, 256, 1024, 1);
    g64_k<0, 0><<<dim3(16, 2, 16), 256, 0, stream>>>(wc2, 0, 256, t1, (long)256 * 1024, 1024,
                                                     bc2, t2, nullptr, 256, 128, 1024, 1);
    g64_k<0, 0><<<dim3(16, 1, 16), 256, 0, stream>>>(wc3, 0, 128, t2, (long)128 * 1024, 1024,
                                                     bc3, fc_c, nullptr, 128, 32, 1024, 0);

    // 10-12: fs_ chain on fs0 (centered style)
    conv3x3_k<<<dim3(15, 4, 16), 256, 0, stream>>>(fs0, Wt1, bs1, s1, 512, 256, 32, 32, 30, 30, 1);
    conv3x3_k<<<dim3(14, 2, 16), 256, 0, stream>>>(s1, Wt2, bs2, s2, 256, 128, 30, 30, 28, 28, 1);
    g64_k<0, 0><<<dim3(13, 1, 16), 256, 0, stream>>>(ws3, 0, 128, s2, (long)128 * 784, 784,
                                                     bs3, fs_c, nullptr, 128, 32, 784, 0);

    // 13: cov
    cov_k<<<B, 1024, 0, stream>>>(fs_c, cov, 32, 784);
    // 14: out32 = cov @ fc_   (batched A: pstride=32*32)
    g64_k<0, 0><<<dim3(16, 1, 16), 256, 0, stream>>>(cov, 1024, 32, fc_c, (long)32 * 1024, 1024,
                                                     nullptr, out32, nullptr, 32, 32, 1024, 0);
    // 15: part2 = conv1x1(out32, w_unc, b_unc)
    g64_k<0, 0><<<dim3(16, 8, 16), 256, 0, stream>>>(w_unc, 0, 32, out32, (long)32 * 1024, 1024,
                                                     b_unc, part2, nullptr, 32, 512, 1024, 0);

    // 16-17: SANet F/G projections (last uses of cn, sn)
    g64_k<0, 0><<<dim3(16, 8, 16), 256, 0, stream>>>(wf_san, 0, 512, cn, (long)C * HW, HW,
                                                     bf_san, Fsb, nullptr, 512, 512, 1024, 0);
    g64_k<0, 0><<<dim3(16, 8, 16), 256, 0, stream>>>(wg_san, 0, 512, sn, (long)C * HW, HW,
                                                     bg_san, Gsb, nullptr, 512, 512, 1024, 0);

    // 18-19: logits S[i][j] = sum_c F[c][i]G[c][j]  (S overlays A+B), softmax
    g64_k<1, 0><<<dim3(16, 16, 16), 256, 0, stream>>>(Fsb, (long)C * HW, HW, Gsb, (long)C * HW, HW,
                                                      nullptr, Sbuf, nullptr, 512, 1024, 1024, 0);
    softmax_k<<<B * HW, 256, 0, stream>>>(Sbuf);

    // 20: H projection (into G slot; Wt1/Wt2 dead after convs)
    g64_k<0, 0><<<dim3(16, 8, 16), 256, 0, stream>>>(wh_san, 0, 512, style, (long)C * HW, HW,
                                                     bh_san, Hsb, nullptr, 512, 512, 1024, 0);

    // 21: part3[c][i] = sum_j H[c][j] S[i][j]
    g64_k<0, 1><<<dim3(16, 8, 16), 256, 0, stream>>>(Hsb, (long)C * HW, HW, Sbuf, (long)HW * HW, HW,
                                                     nullptr, part3, nullptr, 1024, 512, 1024, 0);

    // 22: p = cbrt(relu(part1*part2*part3))
    fuse_k<<<(unsigned)((NE + 255) / 256), 256, 0, stream>>>(ffc, fc2t, part2, part3, pbuf, B, C, HW);

    // 23: out = conv1x1(p, w_out, b_out) + content
    g64_k<0, 0><<<dim3(16, 8, 16), 256, 0, stream>>>(w_out, 0, 512, pbuf, (long)C * HW, HW,
                                                     b_out, (float*)d_out, content, 512, 512, 1024, 0);
}

// Round 5
// 1508.571 us; speedup vs baseline: 3.5682x; 1.9320x over previous
//
#include <hip/hip_runtime.h>
#include <hip/hip_bf16.h>
#include <math.h>

// MFMA bf16 pipeline (fp32 accumulate). fp32 kept for: g-branch GEMM (ill-
// conditioned sum(g^2)/sum(g)), softmax logits S, stats, final output+residual.

typedef __attribute__((ext_vector_type(8))) short short8;
typedef __attribute__((ext_vector_type(4))) float f32x4;
#define MFMA16 __builtin_amdgcn_mfma_f32_16x16x32_bf16

__device__ inline float b2f(unsigned short b) { return __uint_as_float(((unsigned)b) << 16); }
__device__ inline unsigned short f2b(float f) {
    unsigned u = __float_as_uint(f);
    return (unsigned short)((u + 0x7FFFu + ((u >> 16) & 1u)) >> 16);
}

__device__ inline double blockReduceSumD(double v, double* sh) {
    int t = threadIdx.x;
    sh[t] = v; __syncthreads();
    for (int s = blockDim.x >> 1; s > 0; s >>= 1) {
        if (t < s) sh[t] += sh[t + s];
        __syncthreads();
    }
    double r = sh[0]; __syncthreads();
    return r;
}

// ---------- MVN: optional fp32-normalized, bf16-normalized, bf16-centered ----------
__global__ __launch_bounds__(256) void mvn_k(const float* __restrict__ X,
                                             float* __restrict__ Yn32,
                                             unsigned short* __restrict__ Ynb,
                                             unsigned short* __restrict__ Ycb, int HW) {
    __shared__ double sh[256];
    int bc = blockIdx.x;
    const float* x = X + (size_t)bc * HW;
    int t = threadIdx.x;
    float v[4];
    double s = 0.0;
    #pragma unroll
    for (int r = 0; r < 4; ++r) { v[r] = x[t + r * 256]; s += (double)v[r]; }
    double tot = blockReduceSumD(s, sh);
    double ss = 0.0;
    #pragma unroll
    for (int r = 0; r < 4; ++r) ss += (double)v[r] * (double)v[r];
    double tot2 = blockReduceSumD(ss, sh);
    double mean = tot / HW;
    double var = (tot2 - tot * tot / HW) / (HW - 1);
    float inv = (float)(1.0 / sqrt(var + 1e-5));
    float m = (float)mean;
    #pragma unroll
    for (int r = 0; r < 4; ++r) {
        size_t idx = (size_t)bc * HW + t + r * 256;
        float c = v[r] - m;
        if (Yn32) Yn32[idx] = c * inv;
        if (Ynb) Ynb[idx] = f2b(c * inv);
        if (Ycb) Ycb[idx] = f2b(c);
    }
}

// ---------- staging helpers for MFMA GEMM ----------
template <typename TE>
__device__ inline void stage16(const TE* __restrict__ src, bool valid, unsigned short* dst) {
    unsigned short tmp[16];
    if (valid) {
        if constexpr (sizeof(TE) == 2) {
            uint4 a = ((const uint4*)src)[0], b = ((const uint4*)src)[1];
            *(uint4*)&tmp[0] = a; *(uint4*)&tmp[8] = b;
        } else {
            #pragma unroll
            for (int i = 0; i < 16; ++i) tmp[i] = f2b(((const float*)src)[i]);
        }
    } else {
        #pragma unroll
        for (int i = 0; i < 16; ++i) tmp[i] = 0;
    }
    ((uint4*)dst)[0] = *(uint4*)&tmp[0];
    ((uint4*)dst)[1] = *(uint4*)&tmp[8];
}

template <typename TE>
__device__ inline void stageT16(const TE* __restrict__ src, long stride, bool valid,
                                unsigned short* dst) {
    unsigned short tmp[16];
    #pragma unroll
    for (int i = 0; i < 16; ++i) {
        if (valid) {
            if constexpr (sizeof(TE) == 2) tmp[i] = ((const unsigned short*)src)[(long)i * stride];
            else tmp[i] = f2b(((const float*)src)[(long)i * stride]);
        } else tmp[i] = 0;
    }
    ((uint4*)dst)[0] = *(uint4*)&tmp[0];
    ((uint4*)dst)[1] = *(uint4*)&tmp[8];
}

// ---------- 128x128 MFMA GEMM ----------
// D[b][m][n] = act(sum_k A[m][k]*B[k][n] + bias[m]) (+ add_src, fp32)
// TRA=0: A global [m][k] k-contig (lda=row stride). TRA=1: A global [k][m] m-contig.
// TRB=0: B global [k][n] n-contig.                  TRB=1: B global [n][k] k-contig.
template <typename TAel, typename TBel, int TRA, int TRB, typename TOUT>
__global__ __launch_bounds__(256) void mf_k(const TAel* __restrict__ A, long astride, int lda,
                                            const TBel* __restrict__ B, long bstride, int ldb,
                                            const float* __restrict__ bias,
                                            TOUT* __restrict__ Y,
                                            const float* __restrict__ add_src,
                                            int K, int M, int N, int relu) {
    __shared__ unsigned short As[128][40];
    __shared__ unsigned short Bs[128][40];
    int bz = blockIdx.z;
    int mbase = blockIdx.y * 128, nbase = blockIdx.x * 128;
    const TAel* Ab = A + (size_t)bz * astride;
    const TBel* Bb = B + (size_t)bz * bstride;
    int t = threadIdx.x;
    int row = t & 127, kh = t >> 7;                 // staging coords
    int wave = t >> 6, lane = t & 63, lm = lane & 15, q = lane >> 4;
    int mh = (wave >> 1) * 64, nh = (wave & 1) * 64;

    f32x4 acc[4][4];
    #pragma unroll
    for (int i = 0; i < 4; ++i)
        #pragma unroll
        for (int j = 0; j < 4; ++j) acc[i][j] = (f32x4){0.f, 0.f, 0.f, 0.f};

    for (int kb = 0; kb < K; kb += 32) {
        if (TRA == 0) {
            int gm = mbase + row;
            stage16(Ab + (size_t)gm * lda + kb + kh * 16, gm < M, &As[row][kh * 16]);
        } else {
            int gm = mbase + row;
            stageT16(Ab + (size_t)(kb + kh * 16) * lda + gm, lda, gm < M, &As[row][kh * 16]);
        }
        if (TRB == 0) {
            int gn = nbase + row;
            stageT16(Bb + (size_t)(kb + kh * 16) * ldb + gn, ldb, gn < N, &Bs[row][kh * 16]);
        } else {
            int gn = nbase + row;
            stage16(Bb + (size_t)gn * ldb + kb + kh * 16, gn < N, &Bs[row][kh * 16]);
        }
        __syncthreads();
        short8 af[4], bf[4];
        #pragma unroll
        for (int i = 0; i < 4; ++i) af[i] = *(const short8*)&As[mh + i * 16 + lm][q * 8];
        #pragma unroll
        for (int j = 0; j < 4; ++j) bf[j] = *(const short8*)&Bs[nh + j * 16 + lm][q * 8];
        #pragma unroll
        for (int i = 0; i < 4; ++i)
            #pragma unroll
            for (int j = 0; j < 4; ++j)
                acc[i][j] = MFMA16(af[i], bf[j], acc[i][j], 0, 0, 0);
        __syncthreads();
    }

    #pragma unroll
    for (int i = 0; i < 4; ++i) {
        #pragma unroll
        for (int r = 0; r < 4; ++r) {
            int m = mbase + mh + i * 16 + q * 4 + r;
            if (m >= M) continue;
            float bv = bias ? bias[m] : 0.f;
            size_t rowoff = ((size_t)bz * M + m) * (size_t)N;
            #pragma unroll
            for (int j = 0; j < 4; ++j) {
                int n = nbase + nh + j * 16 + lm;
                if (n >= N) continue;
                float v = acc[i][j][r] + bv;
                if (relu) v = (v > 0.f) ? v : 0.f;
                if (add_src) v += add_src[rowoff + n];
                if constexpr (sizeof(TOUT) == 2) Y[rowoff + n] = f2b(v);
                else Y[rowoff + n] = v;
            }
        }
    }
}

// ---------- conv3x3 weight reorder: Wr[tap][o][c] (bf16) from W[o][c][tap] (fp32) ----------
__global__ __launch_bounds__(256) void reorder_w3_k(const float* __restrict__ W,
                                                    unsigned short* __restrict__ Wr,
                                                    int O, int Cin) {
    int idx = blockIdx.x * 256 + threadIdx.x;
    int total = 9 * O * Cin;
    if (idx >= total) return;
    int tap = idx / (O * Cin);
    int rem = idx - tap * (O * Cin);
    int o = rem / Cin;
    int c = rem - o * Cin;
    Wr[idx] = f2b(W[((size_t)o * Cin + c) * 9 + tap]);
}

// ---------- MFMA conv3x3 VALID (relu fused) ----------
// Block: 64 out-ch x (2 out rows x 32 cols). Patch LDS [4 rows][36 cols][c 40pad],
// weights LDS [tap][64 o][c 40pad]; 9 taps reuse one patch per 32-channel k-iter.
__global__ __launch_bounds__(256) void conv_mf_k(const unsigned short* __restrict__ X, long xbstride,
                                                 const unsigned short* __restrict__ Wr,
                                                 const float* __restrict__ bias,
                                                 unsigned short* __restrict__ Y, long ybstride,
                                                 int Cin, int O, int IH, int IWp,
                                                 int OH, int OW, int OWp) {
    __shared__ unsigned short patch[4 * 36 * 40];
    __shared__ unsigned short Ws[9 * 64 * 40];
    int bz = blockIdx.z;
    int obase = blockIdx.y * 64;
    int pyb = blockIdx.x * 2;
    const unsigned short* Xb = X + (size_t)bz * xbstride;
    int t = threadIdx.x;
    int wave = t >> 6, lane = t & 63, lm = lane & 15, q = lane >> 4;
    int mh = (wave >> 1) * 32, rw = wave & 1;

    f32x4 acc[2][2];
    #pragma unroll
    for (int i = 0; i < 2; ++i)
        #pragma unroll
        for (int j = 0; j < 2; ++j) acc[i][j] = (f32x4){0.f, 0.f, 0.f, 0.f};

    // zero pad cols 32..35 (read only by masked outputs; keep finite/zero)
    for (int i = t; i < 4 * 4 * 40; i += 256) {
        int r = i / (4 * 40), rem = i - r * (4 * 40);
        int x = 32 + rem / 40, c = rem - (rem / 40) * 40;
        patch[(r * 36 + x) * 40 + c] = 0;
    }

    for (int cb = 0; cb < Cin; cb += 32) {
        __syncthreads();
        {   // patch: thread t -> c = t&31, (r, xhalf) = t>>5
            int c = t & 31, rx = t >> 5;
            int r = rx >> 1, xh = rx & 1;
            const unsigned short* src = Xb + ((size_t)(cb + c) * IH + (pyb + r)) * IWp + xh * 16;
            uint4 v0 = ((const uint4*)src)[0];
            uint4 v1 = ((const uint4*)src)[1];
            unsigned short tmp[16];
            *(uint4*)&tmp[0] = v0; *(uint4*)&tmp[8] = v1;
            int xb0 = xh * 16;
            #pragma unroll
            for (int i = 0; i < 16; ++i)
                patch[(r * 36 + xb0 + i) * 40 + c] = tmp[i];
        }
        // weights: rows (tap*64 + o_local), 32 ch each
        for (int rowi = t; rowi < 576; rowi += 256) {
            int o_local = rowi & 63, tap = rowi >> 6;
            const unsigned short* src = Wr + ((size_t)tap * O + obase + o_local) * Cin + cb;
            uint4 a = ((const uint4*)src)[0], b = ((const uint4*)src)[1];
            uint4 c2 = ((const uint4*)src)[2], d = ((const uint4*)src)[3];
            unsigned short* dst = &Ws[rowi * 40];
            ((uint4*)dst)[0] = a; ((uint4*)dst)[1] = b;
            ((uint4*)dst)[2] = c2; ((uint4*)dst)[3] = d;
        }
        __syncthreads();
        #pragma unroll
        for (int tap = 0; tap < 9; ++tap) {
            int ky = tap / 3, kx = tap - ky * 3;
            short8 a0 = *(const short8*)&Ws[(tap * 64 + mh + lm) * 40 + q * 8];
            short8 a1 = *(const short8*)&Ws[(tap * 64 + mh + 16 + lm) * 40 + q * 8];
            int prow = (rw + ky) * 36;
            short8 b0 = *(const short8*)&patch[(prow + lm + kx) * 40 + q * 8];
            short8 b1 = *(const short8*)&patch[(prow + 16 + lm + kx) * 40 + q * 8];
            acc[0][0] = MFMA16(a0, b0, acc[0][0], 0, 0, 0);
            acc[0][1] = MFMA16(a0, b1, acc[0][1], 0, 0, 0);
            acc[1][0] = MFMA16(a1, b0, acc[1][0], 0, 0, 0);
            acc[1][1] = MFMA16(a1, b1, acc[1][1], 0, 0, 0);
        }
    }

    int py = pyb + rw;
    #pragma unroll
    for (int i = 0; i < 2; ++i) {
        #pragma unroll
        for (int r = 0; r < 4; ++r) {
            int o = obase + mh + i * 16 + q * 4 + r;
            float bv = bias[o];
            size_t base = (((size_t)bz * O + o) * OH + py) * (size_t)OWp;
            #pragma unroll
            for (int j = 0; j < 2; ++j) {
                int px = j * 16 + lm;
                if (px < OW) {
                    float v = acc[i][j][r] + bv;
                    v = (v > 0.f) ? v : 0.f;
                    Y[base + px] = f2b(v);
                }
            }
        }
    }
}

// ---------- fp32 64x64 VALU GEMM (g-branch + tiny out32) ----------
__device__ inline float4 ld4_guard(const float* __restrict__ row, int n, int N) {
    if (n + 3 < N) return *(const float4*)(row + n);
    float4 v = make_float4(0.f, 0.f, 0.f, 0.f);
    if (n < N) v.x = row[n];
    if (n + 1 < N) v.y = row[n + 1];
    if (n + 2 < N) v.z = row[n + 2];
    return v;
}

__global__ __launch_bounds__(256) void g64_k(const float* __restrict__ P, long pstride, int lda,
                                             const float* __restrict__ Q, long qstride, int ldb,
                                             const float* __restrict__ bias,
                                             float* __restrict__ Y,
                                             int K, int M, int N, int relu) {
    int bb = blockIdx.z;
    int mbase = blockIdx.y * 64;
    int nbase = blockIdx.x * 64;
    const float* Pb = P + (size_t)bb * pstride;
    const float* Qb = Q + (size_t)bb * qstride;

    __shared__ float As[16][68];
    __shared__ float Bs[16][68];

    int t = threadIdx.x;
    int tx = t & 15, ty = t >> 4;
    float acc[4][4] = {{0}, {0}, {0}, {0}};

    for (int cb = 0; cb < K; cb += 16) {
        {
            int mm = t >> 2, k4 = (t & 3) * 4;
            int m = mbase + mm;
            float4 a = (m < M) ? *(const float4*)&Pb[(size_t)m * lda + cb + k4]
                               : make_float4(0.f, 0.f, 0.f, 0.f);
            As[k4 + 0][mm] = a.x; As[k4 + 1][mm] = a.y;
            As[k4 + 2][mm] = a.z; As[k4 + 3][mm] = a.w;
            int k = t >> 4, n4 = (t & 15) * 4;
            float4 b = ld4_guard(&Qb[(size_t)(cb + k) * ldb], nbase + n4, N);
            *(float4*)&Bs[k][n4] = b;
        }
        __syncthreads();
        #pragma unroll
        for (int k = 0; k < 16; ++k) {
            float4 a = *(const float4*)&As[k][ty * 4];
            float4 b = *(const float4*)&Bs[k][tx * 4];
            acc[0][0] += a.x * b.x; acc[0][1] += a.x * b.y; acc[0][2] += a.x * b.z; acc[0][3] += a.x * b.w;
            acc[1][0] += a.y * b.x; acc[1][1] += a.y * b.y; acc[1][2] += a.y * b.z; acc[1][3] += a.y * b.w;
            acc[2][0] += a.z * b.x; acc[2][1] += a.z * b.y; acc[2][2] += a.z * b.z; acc[2][3] += a.z * b.w;
            acc[3][0] += a.w * b.x; acc[3][1] += a.w * b.y; acc[3][2] += a.w * b.z; acc[3][3] += a.w * b.w;
        }
        __syncthreads();
    }
    #pragma unroll
    for (int i = 0; i < 4; ++i) {
        int m = mbase + ty * 4 + i;
        if (m >= M) continue;
        float bv = bias ? bias[m] : 0.f;
        size_t rowoff = ((size_t)bb * M + m) * N;
        #pragma unroll
        for (int j = 0; j < 4; ++j) {
            int n = nbase + tx * 4 + j;
            if (n >= N) continue;
            float v = acc[i][j] + bv;
            if (relu) v = (v > 0.f) ? v : 0.f;
            Y[rowoff + n] = v;
        }
    }
}

// ---------- legacy 32x32 fp32 GEMM (w_fc, N=16) ----------
__global__ __launch_bounds__(256) void gemm_k(const float* __restrict__ W,
                                              const float* __restrict__ X,
                                              const float* __restrict__ bias,
                                              float* __restrict__ Y,
                                              int C, int O, int N) {
    int obase = blockIdx.y * 32;
    __shared__ float As[32][33];
    __shared__ float Bs[32][33];
    int t = threadIdx.x;
    int tx = t & 15, ty = t >> 4;
    float acc00 = 0, acc01 = 0, acc10 = 0, acc11 = 0;
    for (int cb = 0; cb < C; cb += 32) {
        int k = t & 31, o0 = t >> 5;
        #pragma unroll
        for (int r = 0; r < 4; ++r) {
            int ol = o0 + r * 8;
            As[k][ol] = W[(size_t)(obase + ol) * C + cb + k];
        }
        int n0 = t & 31, k0 = t >> 5;
        #pragma unroll
        for (int r = 0; r < 4; ++r) {
            int k2 = k0 + r * 8;
            Bs[k2][n0] = (n0 < N) ? X[(size_t)(cb + k2) * N + n0] : 0.f;
        }
        __syncthreads();
        #pragma unroll
        for (int k2 = 0; k2 < 32; ++k2) {
            float a0 = As[k2][ty], a1 = As[k2][ty + 16];
            float b0 = Bs[k2][tx], b1 = Bs[k2][tx + 16];
            acc00 += a0 * b0; acc01 += a0 * b1;
            acc10 += a1 * b0; acc11 += a1 * b1;
        }
        __syncthreads();
    }
    float accs[2][2] = {{acc00, acc01}, {acc10, acc11}};
    #pragma unroll
    for (int i = 0; i < 2; ++i) {
        int o = obase + ty + i * 16;
        float bv = bias[o];
        #pragma unroll
        for (int j = 0; j < 2; ++j) {
            int n = tx + j * 16;
            if (n < N) Y[(size_t)o * N + n] = accs[i][j] + bv;
        }
    }
}

// ---------- FC_S reduction (fp32 g) ----------
__global__ __launch_bounds__(256) void fcs_k(const float* __restrict__ g,
                                             float* __restrict__ fcs, int HW, int B, int C) {
    __shared__ double sh[256];
    int bc = blockIdx.x;
    int b = bc / C, c = bc - b * C;
    const float* x = g + (size_t)bc * HW;
    double s = 0.0, ss = 0.0;
    for (int i = threadIdx.x; i < HW; i += 256) {
        double v = (double)x[i];
        s += v; ss += v * v;
    }
    double ts = blockReduceSumD(s, sh);
    double tss = blockReduceSumD(ss, sh);
    if (threadIdx.x == 0) fcs[(size_t)c * B + b] = (float)(tss / ts);
}

// ---------- softmax fp32 -> bf16 P ----------
__global__ __launch_bounds__(256) void softmax_k(const float* __restrict__ S,
                                                 unsigned short* __restrict__ P) {
    __shared__ float sh[256];
    size_t row = blockIdx.x;
    const float* r = S + row * 1024;
    unsigned short* po = P + row * 1024;
    int t = threadIdx.x;
    float v[4];
    float m = -INFINITY;
    #pragma unroll
    for (int i = 0; i < 4; ++i) { v[i] = r[t + i * 256]; m = fmaxf(m, v[i]); }
    sh[t] = m; __syncthreads();
    for (int s = 128; s > 0; s >>= 1) { if (t < s) sh[t] = fmaxf(sh[t], sh[t + s]); __syncthreads(); }
    m = sh[0]; __syncthreads();
    float sum = 0;
    #pragma unroll
    for (int i = 0; i < 4; ++i) { v[i] = expf(v[i] - m); sum += v[i]; }
    sh[t] = sum; __syncthreads();
    for (int s = 128; s > 0; s >>= 1) { if (t < s) sh[t] += sh[t + s]; __syncthreads(); }
    float inv = 1.f / sh[0]; __syncthreads();
    #pragma unroll
    for (int i = 0; i < 4; ++i) po[t + i * 256] = f2b(v[i] * inv);
}

// ---------- covariance (fp32 fs_c) ----------
__global__ __launch_bounds__(1024) void cov_k(const float* __restrict__ fs,
                                              float* __restrict__ cov, int Cd, int M) {
    int bb = blockIdx.x;
    int t = threadIdx.x;
    int c = t >> 5, d = t & 31;
    const float* p = fs + (size_t)bb * Cd * M;
    float s = 0;
    for (int i = 0; i < M; ++i) s += p[(size_t)c * M + i] * p[(size_t)d * M + i];
    cov[((size_t)bb * Cd + c) * Cd + d] = s / M;
}

// ---------- fused epilogue: p = cbrt(relu(part1*part2*part3)) ----------
__global__ __launch_bounds__(256) void fuse_k(const unsigned short* __restrict__ ffc,
                                              const float* __restrict__ fc2t,
                                              const unsigned short* __restrict__ p2,
                                              const unsigned short* __restrict__ p3,
                                              unsigned short* __restrict__ out, int B, int C, int N) {
    size_t idx = (size_t)blockIdx.x * 256 + threadIdx.x;
    size_t total = (size_t)B * C * N;
    if (idx >= total) return;
    int c = (int)((idx / N) % C);
    int b = (int)(idx / ((size_t)N * C));
    float part1 = b2f(ffc[idx]) * fc2t[(size_t)c * B + b];
    float v = part1 * b2f(p2[idx]) * b2f(p3[idx]);
    v = (v > 0.f) ? v : 0.f;
    out[idx] = f2b(cbrtf(v));
}

// ---------- launch ----------
extern "C" void kernel_launch(void* const* d_in, const int* in_sizes, int n_in,
                              void* d_out, int out_size, void* d_ws, size_t ws_size,
                              hipStream_t stream) {
    typedef const float* fp;
    fp content = (fp)d_in[0];
    fp style   = (fp)d_in[1];
    fp wf_san = (fp)d_in[2],  bf_san = (fp)d_in[3];
    fp wg_san = (fp)d_in[4],  bg_san = (fp)d_in[5];
    fp wh_san = (fp)d_in[6],  bh_san = (fp)d_in[7];
    fp wf_mcc = (fp)d_in[8],  bf_mcc = (fp)d_in[9];
    fp wg_mcc = (fp)d_in[10], bg_mcc = (fp)d_in[11];
    fp w_fc   = (fp)d_in[12], b_fc   = (fp)d_in[13];
    fp w_out  = (fp)d_in[14], b_out  = (fp)d_in[15];
    fp wc1 = (fp)d_in[16], bc1 = (fp)d_in[17];
    fp wc2 = (fp)d_in[18], bc2 = (fp)d_in[19];
    fp wc3 = (fp)d_in[20], bc3 = (fp)d_in[21];
    fp ws1 = (fp)d_in[22], bs1 = (fp)d_in[23];
    fp ws2 = (fp)d_in[24], bs2 = (fp)d_in[25];
    fp ws3 = (fp)d_in[26], bs3 = (fp)d_in[27];
    fp w_unc = (fp)d_in[28], b_unc = (fp)d_in[29];

    const int B = 16, C = 512, HW = 1024;
    const size_t NE = (size_t)B * C * HW;  // 8388608
    typedef unsigned short us;
    char* base = (char*)d_ws;

    // byte-offset layout (total ~217 MB)
    float* sn32  = (float*)(base + 0);            // 33.55 MB, dead after g-GEMM
    float* g32   = (float*)(base + 33554432);     // 33.55 MB, dead after fcs
    float* Sbuf  = (float*)(base + 0);            // 67.1 MB overlay (logits)
    us* cnb  = (us*)(base + 67108864);
    us* snb  = (us*)(base + 83886080);
    us* fs0b = (us*)(base + 100663296);
    us* ffcb = (us*)(base + 117440512);           // -> p (in place)
    char* scr = base + 134217728;                 // 33.55 MB scratch region
    us* t1 = (us*)scr;                            // 16*256*1024
    us* t2 = (us*)(scr + 8388608);                // 16*128*1024
    us* s1 = (us*)scr;                            // 16*256*30*32 (OWp=32 padded)
    us* s2 = (us*)(scr + 7864320);                // 16*128*28*28
    us* Pb = (us*)scr;                            // 16*1024*1024 bf16 (after convs)
    us* Wr1 = (us*)(base + 167772160);            // 9*256*512
    us* Wr2 = (us*)(base + 170131456);            // 9*128*256
    float* fc_c  = (float*)(base + 170721280);    // 16*32*1024
    float* fs_c  = (float*)(base + 172818432);    // 16*32*784
    float* out32 = (float*)(base + 174424064);    // 16*32*1024
    float* fcs   = (float*)(base + 176521216);    // 512*16
    float* fc2t  = (float*)(base + 176553984);    // 512*16
    float* cov   = (float*)(base + 176586752);    // 16*32*32
    us* part2 = (us*)(base + 176652288);
    us* Fsb   = (us*)(base + 193429504);          // -> Hsb after logits
    us* Gsb   = (us*)(base + 210206720);          // -> part3 after logits
    us* Hsb = Fsb;
    us* part3 = Gsb;
    us* pbuf = ffcb;

    // 0: conv weights -> bf16 [tap][o][c]
    reorder_w3_k<<<4608, 256, 0, stream>>>(ws1, Wr1, 256, 512);
    reorder_w3_k<<<1152, 256, 0, stream>>>(ws2, Wr2, 128, 256);

    // 1-2: MVN (content -> cnb; style -> sn32 + snb + fs0b)
    mvn_k<<<B * C, 256, 0, stream>>>(content, nullptr, cnb, nullptr, HW);
    mvn_k<<<B * C, 256, 0, stream>>>(style, sn32, snb, fs0b, HW);

    // 3: g = conv1x1(sn, wg_mcc) fp32 (ill-conditioned branch stays fp32)
    g64_k<<<dim3(16, 8, 16), 256, 0, stream>>>(wg_mcc, 0, 512, sn32, (long)C * HW, HW,
                                               bg_mcc, g32, 512, 512, 1024, 0);
    // 4: FC_S stats + linear
    fcs_k<<<B * C, 256, 0, stream>>>(g32, fcs, HW, B, C);
    gemm_k<<<dim3(1, 16, 1), 256, 0, stream>>>(w_fc, fcs, b_fc, fc2t, 512, 512, 16);

    // 5: F_Fc = wf_mcc . cn
    mf_k<float, us, 0, 0, us><<<dim3(8, 4, 16), 256, 0, stream>>>(
        wf_mcc, 0, 512, cnb, (long)C * HW, HW, bf_mcc, ffcb, nullptr, 512, 512, 1024, 0);

    // 6-8: fc chain
    mf_k<float, us, 0, 0, us><<<dim3(8, 2, 16), 256, 0, stream>>>(
        wc1, 0, 512, cnb, (long)C * HW, HW, bc1, t1, nullptr, 512, 256, 1024, 1);
    mf_k<float, us, 0, 0, us><<<dim3(8, 1, 16), 256, 0, stream>>>(
        wc2, 0, 256, t1, (long)256 * 1024, 1024, bc2, t2, nullptr, 256, 128, 1024, 1);
    mf_k<float, us, 0, 0, float><<<dim3(8, 1, 16), 256, 0, stream>>>(
        wc3, 0, 128, t2, (long)128 * 1024, 1024, bc3, fc_c, nullptr, 128, 32, 1024, 0);

    // 9-10: conv3x3 chain (relu fused); s1 stored row-padded to 32
    conv_mf_k<<<dim3(15, 4, 16), 256, 0, stream>>>(fs0b, (long)512 * 32 * 32, Wr1, bs1,
                                                   s1, (long)256 * 30 * 32, 512, 256, 32, 32, 30, 30, 32);
    conv_mf_k<<<dim3(14, 2, 16), 256, 0, stream>>>(s1, (long)256 * 30 * 32, Wr2, bs2,
                                                   s2, (long)128 * 28 * 28, 256, 128, 30, 32, 28, 28, 28);
    // 11: fs_c = ws3 . s2 (fp32 out)
    mf_k<float, us, 0, 0, float><<<dim3(7, 1, 16), 256, 0, stream>>>(
        ws3, 0, 128, s2, (long)128 * 784, 784, bs3, fs_c, nullptr, 128, 32, 784, 0);

    // 12-14: cov, out32, part2
    cov_k<<<B, 1024, 0, stream>>>(fs_c, cov, 32, 784);
    g64_k<<<dim3(16, 1, 16), 256, 0, stream>>>(cov, 1024, 32, fc_c, (long)32 * 1024, 1024,
                                               nullptr, out32, 32, 32, 1024, 0);
    mf_k<float, float, 0, 0, us><<<dim3(8, 4, 16), 256, 0, stream>>>(
        w_unc, 0, 32, out32, (long)32 * 1024, 1024, b_unc, part2, nullptr, 32, 512, 1024, 0);

    // 15-16: SANet F/G projections (last uses of cnb, snb)
    mf_k<float, us, 0, 0, us><<<dim3(8, 4, 16), 256, 0, stream>>>(
        wf_san, 0, 512, cnb, (long)C * HW, HW, bf_san, Fsb, nullptr, 512, 512, 1024, 0);
    mf_k<float, us, 0, 0, us><<<dim3(8, 4, 16), 256, 0, stream>>>(
        wg_san, 0, 512, snb, (long)C * HW, HW, bg_san, Gsb, nullptr, 512, 512, 1024, 0);

    // 17: logits S[i][j] = sum_c F[c][i] G[c][j]  (fp32 out, overlays sn32/g32)
    mf_k<us, us, 1, 0, float><<<dim3(8, 8, 16), 256, 0, stream>>>(
        Fsb, (long)C * HW, HW, Gsb, (long)C * HW, HW, nullptr, Sbuf, nullptr, 512, 1024, 1024, 0);
    // 18: softmax -> bf16 P (overlays t1/t2/s1/s2, all dead)
    softmax_k<<<B * HW, 256, 0, stream>>>(Sbuf, Pb);

    // 19: H projection (style fp32 input) into Fsb slot
    mf_k<float, float, 0, 0, us><<<dim3(8, 4, 16), 256, 0, stream>>>(
        wh_san, 0, 512, style, (long)C * HW, HW, bh_san, Hsb, nullptr, 512, 512, 1024, 0);
    // 20: part3[c][i] = sum_j H[c][j] P[i][j]
    mf_k<us, us, 0, 1, us><<<dim3(8, 4, 16), 256, 0, stream>>>(
        Hsb, (long)C * HW, HW, Pb, (long)HW * HW, HW, nullptr, part3, nullptr, 1024, 512, 1024, 0);

    // 21: p = cbrt(relu(part1*part2*part3))  (in place over ffcb)
    fuse_k<<<(unsigned)((NE + 255) / 256), 256, 0, stream>>>(ffcb, fc2t, part2, part3, pbuf, B, C, HW);

    // 22: out = w_out . p + b_out + content (fp32)
    mf_k<float, us, 0, 0, float><<<dim3(8, 4, 16), 256, 0, stream>>>(
        w_out, 0, 512, pbuf, (long)C * HW, HW, b_out, (float*)d_out, content, 512, 512, 1024, 0);
}

// Round 6
// 1235.565 us; speedup vs baseline: 4.3566x; 1.2210x over previous
//
#include <hip/hip_runtime.h>
#include <hip/hip_bf16.h>
#include <math.h>

// MFMA bf16 pipeline (fp32 accumulate). fp32 kept for: g-branch GEMM (ill-
// conditioned sum(g^2)/sum(g)), softmax logits S, stats, final output+residual.

typedef __attribute__((ext_vector_type(8))) short short8;
typedef __attribute__((ext_vector_type(4))) float f32x4;
#define MFMA16 __builtin_amdgcn_mfma_f32_16x16x32_bf16

__device__ inline float b2f(unsigned short b) { return __uint_as_float(((unsigned)b) << 16); }
__device__ inline unsigned short f2b(float f) {
    unsigned u = __float_as_uint(f);
    return (unsigned short)((u + 0x7FFFu + ((u >> 16) & 1u)) >> 16);
}

__device__ inline double blockReduceSumD(double v, double* sh) {
    int t = threadIdx.x;
    sh[t] = v; __syncthreads();
    for (int s = blockDim.x >> 1; s > 0; s >>= 1) {
        if (t < s) sh[t] += sh[t + s];
        __syncthreads();
    }
    double r = sh[0]; __syncthreads();
    return r;
}

// ---------- MVN: optional fp32-normalized, bf16-normalized, bf16-centered ----------
__global__ __launch_bounds__(256) void mvn_k(const float* __restrict__ X,
                                             float* __restrict__ Yn32,
                                             unsigned short* __restrict__ Ynb,
                                             unsigned short* __restrict__ Ycb, int HW) {
    __shared__ double sh[256];
    int bc = blockIdx.x;
    const float* x = X + (size_t)bc * HW;
    int t = threadIdx.x;
    float v[4];
    double s = 0.0;
    #pragma unroll
    for (int r = 0; r < 4; ++r) { v[r] = x[t + r * 256]; s += (double)v[r]; }
    double tot = blockReduceSumD(s, sh);
    double ss = 0.0;
    #pragma unroll
    for (int r = 0; r < 4; ++r) ss += (double)v[r] * (double)v[r];
    double tot2 = blockReduceSumD(ss, sh);
    double mean = tot / HW;
    double var = (tot2 - tot * tot / HW) / (HW - 1);
    float inv = (float)(1.0 / sqrt(var + 1e-5));
    float m = (float)mean;
    #pragma unroll
    for (int r = 0; r < 4; ++r) {
        size_t idx = (size_t)bc * HW + t + r * 256;
        float c = v[r] - m;
        if (Yn32) Yn32[idx] = c * inv;
        if (Ynb) Ynb[idx] = f2b(c * inv);
        if (Ycb) Ycb[idx] = f2b(c);
    }
}

// ---------- staging helpers for MFMA GEMM ----------
template <typename TE>
__device__ inline void stage16(const TE* __restrict__ src, bool valid, unsigned short* dst) {
    unsigned short tmp[16];
    if (valid) {
        if constexpr (sizeof(TE) == 2) {
            uint4 a = ((const uint4*)src)[0], b = ((const uint4*)src)[1];
            *(uint4*)&tmp[0] = a; *(uint4*)&tmp[8] = b;
        } else {
            #pragma unroll
            for (int i = 0; i < 16; ++i) tmp[i] = f2b(((const float*)src)[i]);
        }
    } else {
        #pragma unroll
        for (int i = 0; i < 16; ++i) tmp[i] = 0;
    }
    ((uint4*)dst)[0] = *(uint4*)&tmp[0];
    ((uint4*)dst)[1] = *(uint4*)&tmp[8];
}

template <typename TE>
__device__ inline void stageT16(const TE* __restrict__ src, long stride, bool valid,
                                unsigned short* dst) {
    unsigned short tmp[16];
    #pragma unroll
    for (int i = 0; i < 16; ++i) {
        if (valid) {
            if constexpr (sizeof(TE) == 2) tmp[i] = ((const unsigned short*)src)[(long)i * stride];
            else tmp[i] = f2b(((const float*)src)[(long)i * stride]);
        } else tmp[i] = 0;
    }
    ((uint4*)dst)[0] = *(uint4*)&tmp[0];
    ((uint4*)dst)[1] = *(uint4*)&tmp[8];
}

// ---------- 128x128 MFMA GEMM ----------
// D[b][m][n] = act(sum_k A[m][k]*B[k][n] + bias[m]) (+ add_src, fp32)
// TRA=0: A global [m][k] k-contig (lda=row stride). TRA=1: A global [k][m] m-contig.
// TRB=0: B global [k][n] n-contig.                  TRB=1: B global [n][k] k-contig.
template <typename TAel, typename TBel, int TRA, int TRB, typename TOUT>
__global__ __launch_bounds__(256) void mf_k(const TAel* __restrict__ A, long astride, int lda,
                                            const TBel* __restrict__ B, long bstride, int ldb,
                                            const float* __restrict__ bias,
                                            TOUT* __restrict__ Y,
                                            const float* __restrict__ add_src,
                                            int K, int M, int N, int relu) {
    __shared__ unsigned short As[128][40];
    __shared__ unsigned short Bs[128][40];
    int bz = blockIdx.z;
    int mbase = blockIdx.y * 128, nbase = blockIdx.x * 128;
    const TAel* Ab = A + (size_t)bz * astride;
    const TBel* Bb = B + (size_t)bz * bstride;
    int t = threadIdx.x;
    int row = t & 127, kh = t >> 7;                 // staging coords
    int wave = t >> 6, lane = t & 63, lm = lane & 15, q = lane >> 4;
    int mh = (wave >> 1) * 64, nh = (wave & 1) * 64;

    f32x4 acc[4][4];
    #pragma unroll
    for (int i = 0; i < 4; ++i)
        #pragma unroll
        for (int j = 0; j < 4; ++j) acc[i][j] = (f32x4){0.f, 0.f, 0.f, 0.f};

    for (int kb = 0; kb < K; kb += 32) {
        if (TRA == 0) {
            int gm = mbase + row;
            stage16(Ab + (size_t)gm * lda + kb + kh * 16, gm < M, &As[row][kh * 16]);
        } else {
            int gm = mbase + row;
            stageT16(Ab + (size_t)(kb + kh * 16) * lda + gm, lda, gm < M, &As[row][kh * 16]);
        }
        if (TRB == 0) {
            int gn = nbase + row;
            stageT16(Bb + (size_t)(kb + kh * 16) * ldb + gn, ldb, gn < N, &Bs[row][kh * 16]);
        } else {
            int gn = nbase + row;
            stage16(Bb + (size_t)gn * ldb + kb + kh * 16, gn < N, &Bs[row][kh * 16]);
        }
        __syncthreads();
        short8 af[4], bf[4];
        #pragma unroll
        for (int i = 0; i < 4; ++i) af[i] = *(const short8*)&As[mh + i * 16 + lm][q * 8];
        #pragma unroll
        for (int j = 0; j < 4; ++j) bf[j] = *(const short8*)&Bs[nh + j * 16 + lm][q * 8];
        #pragma unroll
        for (int i = 0; i < 4; ++i)
            #pragma unroll
            for (int j = 0; j < 4; ++j)
                acc[i][j] = MFMA16(af[i], bf[j], acc[i][j], 0, 0, 0);
        __syncthreads();
    }

    #pragma unroll
    for (int i = 0; i < 4; ++i) {
        #pragma unroll
        for (int r = 0; r < 4; ++r) {
            int m = mbase + mh + i * 16 + q * 4 + r;
            if (m >= M) continue;
            float bv = bias ? bias[m] : 0.f;
            size_t rowoff = ((size_t)bz * M + m) * (size_t)N;
            #pragma unroll
            for (int j = 0; j < 4; ++j) {
                int n = nbase + nh + j * 16 + lm;
                if (n >= N) continue;
                float v = acc[i][j][r] + bv;
                if (relu) v = (v > 0.f) ? v : 0.f;
                if (add_src) v += add_src[rowoff + n];
                if constexpr (sizeof(TOUT) == 2) Y[rowoff + n] = f2b(v);
                else Y[rowoff + n] = v;
            }
        }
    }
}

// ---------- conv3x3 weight reorder: Wr[tap][o][c] (bf16) from W[o][c][tap] (fp32) ----------
__global__ __launch_bounds__(256) void reorder_w3_k(const float* __restrict__ W,
                                                    unsigned short* __restrict__ Wr,
                                                    int O, int Cin) {
    int idx = blockIdx.x * 256 + threadIdx.x;
    int total = 9 * O * Cin;
    if (idx >= total) return;
    int tap = idx / (O * Cin);
    int rem = idx - tap * (O * Cin);
    int o = rem / Cin;
    int c = rem - o * Cin;
    Wr[idx] = f2b(W[((size_t)o * Cin + c) * 9 + tap]);
}

// ---------- MFMA conv3x3 VALID (relu fused) ----------
__global__ __launch_bounds__(256) void conv_mf_k(const unsigned short* __restrict__ X, long xbstride,
                                                 const unsigned short* __restrict__ Wr,
                                                 const float* __restrict__ bias,
                                                 unsigned short* __restrict__ Y, long ybstride,
                                                 int Cin, int O, int IH, int IWp,
                                                 int OH, int OW, int OWp) {
    __shared__ unsigned short patch[4 * 36 * 40];
    __shared__ unsigned short Ws[9 * 64 * 40];
    int bz = blockIdx.z;
    int obase = blockIdx.y * 64;
    int pyb = blockIdx.x * 2;
    const unsigned short* Xb = X + (size_t)bz * xbstride;
    int t = threadIdx.x;
    int wave = t >> 6, lane = t & 63, lm = lane & 15, q = lane >> 4;
    int mh = (wave >> 1) * 32, rw = wave & 1;

    f32x4 acc[2][2];
    #pragma unroll
    for (int i = 0; i < 2; ++i)
        #pragma unroll
        for (int j = 0; j < 2; ++j) acc[i][j] = (f32x4){0.f, 0.f, 0.f, 0.f};

    for (int i = t; i < 4 * 4 * 40; i += 256) {
        int r = i / (4 * 40), rem = i - r * (4 * 40);
        int x = 32 + rem / 40, c = rem - (rem / 40) * 40;
        patch[(r * 36 + x) * 40 + c] = 0;
    }

    for (int cb = 0; cb < Cin; cb += 32) {
        __syncthreads();
        {
            int c = t & 31, rx = t >> 5;
            int r = rx >> 1, xh = rx & 1;
            const unsigned short* src = Xb + ((size_t)(cb + c) * IH + (pyb + r)) * IWp + xh * 16;
            uint4 v0 = ((const uint4*)src)[0];
            uint4 v1 = ((const uint4*)src)[1];
            unsigned short tmp[16];
            *(uint4*)&tmp[0] = v0; *(uint4*)&tmp[8] = v1;
            int xb0 = xh * 16;
            #pragma unroll
            for (int i = 0; i < 16; ++i)
                patch[(r * 36 + xb0 + i) * 40 + c] = tmp[i];
        }
        for (int rowi = t; rowi < 576; rowi += 256) {
            int o_local = rowi & 63, tap = rowi >> 6;
            const unsigned short* src = Wr + ((size_t)tap * O + obase + o_local) * Cin + cb;
            uint4 a = ((const uint4*)src)[0], b = ((const uint4*)src)[1];
            uint4 c2 = ((const uint4*)src)[2], d = ((const uint4*)src)[3];
            unsigned short* dst = &Ws[rowi * 40];
            ((uint4*)dst)[0] = a; ((uint4*)dst)[1] = b;
            ((uint4*)dst)[2] = c2; ((uint4*)dst)[3] = d;
        }
        __syncthreads();
        #pragma unroll
        for (int tap = 0; tap < 9; ++tap) {
            int ky = tap / 3, kx = tap - ky * 3;
            short8 a0 = *(const short8*)&Ws[(tap * 64 + mh + lm) * 40 + q * 8];
            short8 a1 = *(const short8*)&Ws[(tap * 64 + mh + 16 + lm) * 40 + q * 8];
            int prow = (rw + ky) * 36;
            short8 b0 = *(const short8*)&patch[(prow + lm + kx) * 40 + q * 8];
            short8 b1 = *(const short8*)&patch[(prow + 16 + lm + kx) * 40 + q * 8];
            acc[0][0] = MFMA16(a0, b0, acc[0][0], 0, 0, 0);
            acc[0][1] = MFMA16(a0, b1, acc[0][1], 0, 0, 0);
            acc[1][0] = MFMA16(a1, b0, acc[1][0], 0, 0, 0);
            acc[1][1] = MFMA16(a1, b1, acc[1][1], 0, 0, 0);
        }
    }

    int py = pyb + rw;
    #pragma unroll
    for (int i = 0; i < 2; ++i) {
        #pragma unroll
        for (int r = 0; r < 4; ++r) {
            int o = obase + mh + i * 16 + q * 4 + r;
            float bv = bias[o];
            size_t base = (((size_t)bz * O + o) * OH + py) * (size_t)OWp;
            #pragma unroll
            for (int j = 0; j < 2; ++j) {
                int px = j * 16 + lm;
                if (px < OW) {
                    float v = acc[i][j][r] + bv;
                    v = (v > 0.f) ? v : 0.f;
                    Y[base + px] = f2b(v);
                }
            }
        }
    }
}

// ---------- fp32 64x64 VALU GEMM (g-branch + tiny out32) ----------
__device__ inline float4 ld4_guard(const float* __restrict__ row, int n, int N) {
    if (n + 3 < N) return *(const float4*)(row + n);
    float4 v = make_float4(0.f, 0.f, 0.f, 0.f);
    if (n < N) v.x = row[n];
    if (n + 1 < N) v.y = row[n + 1];
    if (n + 2 < N) v.z = row[n + 2];
    return v;
}

__global__ __launch_bounds__(256) void g64_k(const float* __restrict__ P, long pstride, int lda,
                                             const float* __restrict__ Q, long qstride, int ldb,
                                             const float* __restrict__ bias,
                                             float* __restrict__ Y,
                                             int K, int M, int N, int relu) {
    int bb = blockIdx.z;
    int mbase = blockIdx.y * 64;
    int nbase = blockIdx.x * 64;
    const float* Pb = P + (size_t)bb * pstride;
    const float* Qb = Q + (size_t)bb * qstride;

    __shared__ float As[16][68];
    __shared__ float Bs[16][68];

    int t = threadIdx.x;
    int tx = t & 15, ty = t >> 4;
    float acc[4][4] = {{0}, {0}, {0}, {0}};

    for (int cb = 0; cb < K; cb += 16) {
        {
            int mm = t >> 2, k4 = (t & 3) * 4;
            int m = mbase + mm;
            float4 a = (m < M) ? *(const float4*)&Pb[(size_t)m * lda + cb + k4]
                               : make_float4(0.f, 0.f, 0.f, 0.f);
            As[k4 + 0][mm] = a.x; As[k4 + 1][mm] = a.y;
            As[k4 + 2][mm] = a.z; As[k4 + 3][mm] = a.w;
            int k = t >> 4, n4 = (t & 15) * 4;
            float4 b = ld4_guard(&Qb[(size_t)(cb + k) * ldb], nbase + n4, N);
            *(float4*)&Bs[k][n4] = b;
        }
        __syncthreads();
        #pragma unroll
        for (int k = 0; k < 16; ++k) {
            float4 a = *(const float4*)&As[k][ty * 4];
            float4 b = *(const float4*)&Bs[k][tx * 4];
            acc[0][0] += a.x * b.x; acc[0][1] += a.x * b.y; acc[0][2] += a.x * b.z; acc[0][3] += a.x * b.w;
            acc[1][0] += a.y * b.x; acc[1][1] += a.y * b.y; acc[1][2] += a.y * b.z; acc[1][3] += a.y * b.w;
            acc[2][0] += a.z * b.x; acc[2][1] += a.z * b.y; acc[2][2] += a.z * b.z; acc[2][3] += a.z * b.w;
            acc[3][0] += a.w * b.x; acc[3][1] += a.w * b.y; acc[3][2] += a.w * b.z; acc[3][3] += a.w * b.w;
        }
        __syncthreads();
    }
    #pragma unroll
    for (int i = 0; i < 4; ++i) {
        int m = mbase + ty * 4 + i;
        if (m >= M) continue;
        float bv = bias ? bias[m] : 0.f;
        size_t rowoff = ((size_t)bb * M + m) * N;
        #pragma unroll
        for (int j = 0; j < 4; ++j) {
            int n = nbase + tx * 4 + j;
            if (n >= N) continue;
            float v = acc[i][j] + bv;
            if (relu) v = (v > 0.f) ? v : 0.f;
            Y[rowoff + n] = v;
        }
    }
}

// ---------- legacy 32x32 fp32 GEMM (w_fc, N=16) ----------
__global__ __launch_bounds__(256) void gemm_k(const float* __restrict__ W,
                                              const float* __restrict__ X,
                                              const float* __restrict__ bias,
                                              float* __restrict__ Y,
                                              int C, int O, int N) {
    int obase = blockIdx.y * 32;
    __shared__ float As[32][33];
    __shared__ float Bs[32][33];
    int t = threadIdx.x;
    int tx = t & 15, ty = t >> 4;
    float acc00 = 0, acc01 = 0, acc10 = 0, acc11 = 0;
    for (int cb = 0; cb < C; cb += 32) {
        int k = t & 31, o0 = t >> 5;
        #pragma unroll
        for (int r = 0; r < 4; ++r) {
            int ol = o0 + r * 8;
            As[k][ol] = W[(size_t)(obase + ol) * C + cb + k];
        }
        int n0 = t & 31, k0 = t >> 5;
        #pragma unroll
        for (int r = 0; r < 4; ++r) {
            int k2 = k0 + r * 8;
            Bs[k2][n0] = (n0 < N) ? X[(size_t)(cb + k2) * N + n0] : 0.f;
        }
        __syncthreads();
        #pragma unroll
        for (int k2 = 0; k2 < 32; ++k2) {
            float a0 = As[k2][ty], a1 = As[k2][ty + 16];
            float b0 = Bs[k2][tx], b1 = Bs[k2][tx + 16];
            acc00 += a0 * b0; acc01 += a0 * b1;
            acc10 += a1 * b0; acc11 += a1 * b1;
        }
        __syncthreads();
    }
    float accs[2][2] = {{acc00, acc01}, {acc10, acc11}};
    #pragma unroll
    for (int i = 0; i < 2; ++i) {
        int o = obase + ty + i * 16;
        float bv = bias[o];
        #pragma unroll
        for (int j = 0; j < 2; ++j) {
            int n = tx + j * 16;
            if (n < N) Y[(size_t)o * N + n] = accs[i][j] + bv;
        }
    }
}

// ---------- FC_S reduction (fp32 g) ----------
__global__ __launch_bounds__(256) void fcs_k(const float* __restrict__ g,
                                             float* __restrict__ fcs, int HW, int B, int C) {
    __shared__ double sh[256];
    int bc = blockIdx.x;
    int b = bc / C, c = bc - b * C;
    const float* x = g + (size_t)bc * HW;
    double s = 0.0, ss = 0.0;
    for (int i = threadIdx.x; i < HW; i += 256) {
        double v = (double)x[i];
        s += v; ss += v * v;
    }
    double ts = blockReduceSumD(s, sh);
    double tss = blockReduceSumD(ss, sh);
    if (threadIdx.x == 0) fcs[(size_t)c * B + b] = (float)(tss / ts);
}

// ---------- softmax fp32 -> bf16 P ----------
__global__ __launch_bounds__(256) void softmax_k(const float* __restrict__ S,
                                                 unsigned short* __restrict__ P) {
    __shared__ float sh[256];
    size_t row = blockIdx.x;
    const float* r = S + row * 1024;
    unsigned short* po = P + row * 1024;
    int t = threadIdx.x;
    float v[4];
    float m = -INFINITY;
    #pragma unroll
    for (int i = 0; i < 4; ++i) { v[i] = r[t + i * 256]; m = fmaxf(m, v[i]); }
    sh[t] = m; __syncthreads();
    for (int s = 128; s > 0; s >>= 1) { if (t < s) sh[t] = fmaxf(sh[t], sh[t + s]); __syncthreads(); }
    m = sh[0]; __syncthreads();
    float sum = 0;
    #pragma unroll
    for (int i = 0; i < 4; ++i) { v[i] = expf(v[i] - m); sum += v[i]; }
    sh[t] = sum; __syncthreads();
    for (int s = 128; s > 0; s >>= 1) { if (t < s) sh[t] += sh[t + s]; __syncthreads(); }
    float inv = 1.f / sh[0]; __syncthreads();
    #pragma unroll
    for (int i = 0; i < 4; ++i) po[t + i * 256] = f2b(v[i] * inv);
}

// ---------- covariance: LDS-staged, 4 (c,d) pairs per thread ----------
// Grid: B blocks x 256 threads. fs [32][784] fp32. Chunked 4 x 196, LDS stride 197
// (197%8==5 -> gather banks 0,20,8,28,16,4,24,12 all distinct; broadcast banks c*5%32 distinct).
// Same per-pair summation order as the naive loop -> bit-identical result.
__global__ __launch_bounds__(256) void cov_k(const float* __restrict__ fs,
                                             float* __restrict__ cov, int Cd, int M) {
    __shared__ float Ls[32 * 197];
    int bb = blockIdx.x;
    int t = threadIdx.x;
    const float* p = fs + (size_t)bb * Cd * M;
    int c = t >> 3;             // 0..31
    int d0 = (t & 7) * 4;       // 0,4,...,28
    float a0 = 0.f, a1 = 0.f, a2 = 0.f, a3 = 0.f;

    for (int ch = 0; ch < 4; ++ch) {
        int c0 = ch * 196;
        __syncthreads();
        if (t < 196) {
            #pragma unroll
            for (int r = 0; r < 32; ++r)
                Ls[r * 197 + t] = p[(size_t)r * M + c0 + t];
        }
        __syncthreads();
        const float* rowc = &Ls[c * 197];
        const float* rd0 = &Ls[(d0 + 0) * 197];
        const float* rd1 = &Ls[(d0 + 1) * 197];
        const float* rd2 = &Ls[(d0 + 2) * 197];
        const float* rd3 = &Ls[(d0 + 3) * 197];
        #pragma unroll 4
        for (int i = 0; i < 196; ++i) {
            float a = rowc[i];
            a0 += a * rd0[i];
            a1 += a * rd1[i];
            a2 += a * rd2[i];
            a3 += a * rd3[i];
        }
    }
    float invM = 1.f / (float)M;
    size_t base = ((size_t)bb * Cd + c) * Cd + d0;
    cov[base + 0] = a0 * invM;
    cov[base + 1] = a1 * invM;
    cov[base + 2] = a2 * invM;
    cov[base + 3] = a3 * invM;
}

// ---------- fused epilogue: p = cbrt(relu(part1*part2*part3)) ----------
__global__ __launch_bounds__(256) void fuse_k(const unsigned short* __restrict__ ffc,
                                              const float* __restrict__ fc2t,
                                              const unsigned short* __restrict__ p2,
                                              const unsigned short* __restrict__ p3,
                                              unsigned short* __restrict__ out, int B, int C, int N) {
    size_t idx = (size_t)blockIdx.x * 256 + threadIdx.x;
    size_t total = (size_t)B * C * N;
    if (idx >= total) return;
    int c = (int)((idx / N) % C);
    int b = (int)(idx / ((size_t)N * C));
    float part1 = b2f(ffc[idx]) * fc2t[(size_t)c * B + b];
    float v = part1 * b2f(p2[idx]) * b2f(p3[idx]);
    v = (v > 0.f) ? v : 0.f;
    out[idx] = f2b(cbrtf(v));
}

// ---------- launch ----------
extern "C" void kernel_launch(void* const* d_in, const int* in_sizes, int n_in,
                              void* d_out, int out_size, void* d_ws, size_t ws_size,
                              hipStream_t stream) {
    typedef const float* fp;
    fp content = (fp)d_in[0];
    fp style   = (fp)d_in[1];
    fp wf_san = (fp)d_in[2],  bf_san = (fp)d_in[3];
    fp wg_san = (fp)d_in[4],  bg_san = (fp)d_in[5];
    fp wh_san = (fp)d_in[6],  bh_san = (fp)d_in[7];
    fp wf_mcc = (fp)d_in[8],  bf_mcc = (fp)d_in[9];
    fp wg_mcc = (fp)d_in[10], bg_mcc = (fp)d_in[11];
    fp w_fc   = (fp)d_in[12], b_fc   = (fp)d_in[13];
    fp w_out  = (fp)d_in[14], b_out  = (fp)d_in[15];
    fp wc1 = (fp)d_in[16], bc1 = (fp)d_in[17];
    fp wc2 = (fp)d_in[18], bc2 = (fp)d_in[19];
    fp wc3 = (fp)d_in[20], bc3 = (fp)d_in[21];
    fp ws1 = (fp)d_in[22], bs1 = (fp)d_in[23];
    fp ws2 = (fp)d_in[24], bs2 = (fp)d_in[25];
    fp ws3 = (fp)d_in[26], bs3 = (fp)d_in[27];
    fp w_unc = (fp)d_in[28], b_unc = (fp)d_in[29];

    const int B = 16, C = 512, HW = 1024;
    const size_t NE = (size_t)B * C * HW;  // 8388608
    typedef unsigned short us;
    char* base = (char*)d_ws;

    float* sn32  = (float*)(base + 0);
    float* g32   = (float*)(base + 33554432);
    float* Sbuf  = (float*)(base + 0);
    us* cnb  = (us*)(base + 67108864);
    us* snb  = (us*)(base + 83886080);
    us* fs0b = (us*)(base + 100663296);
    us* ffcb = (us*)(base + 117440512);
    char* scr = base + 134217728;
    us* t1 = (us*)scr;
    us* t2 = (us*)(scr + 8388608);
    us* s1 = (us*)scr;
    us* s2 = (us*)(scr + 7864320);
    us* Pb = (us*)scr;
    us* Wr1 = (us*)(base + 167772160);
    us* Wr2 = (us*)(base + 170131456);
    float* fc_c  = (float*)(base + 170721280);
    float* fs_c  = (float*)(base + 172818432);
    float* out32 = (float*)(base + 174424064);
    float* fcs   = (float*)(base + 176521216);
    float* fc2t  = (float*)(base + 176553984);
    float* cov   = (float*)(base + 176586752);
    us* part2 = (us*)(base + 176652288);
    us* Fsb   = (us*)(base + 193429504);
    us* Gsb   = (us*)(base + 210206720);
    us* Hsb = Fsb;
    us* part3 = Gsb;
    us* pbuf = ffcb;

    reorder_w3_k<<<4608, 256, 0, stream>>>(ws1, Wr1, 256, 512);
    reorder_w3_k<<<1152, 256, 0, stream>>>(ws2, Wr2, 128, 256);

    mvn_k<<<B * C, 256, 0, stream>>>(content, nullptr, cnb, nullptr, HW);
    mvn_k<<<B * C, 256, 0, stream>>>(style, sn32, snb, fs0b, HW);

    g64_k<<<dim3(16, 8, 16), 256, 0, stream>>>(wg_mcc, 0, 512, sn32, (long)C * HW, HW,
                                               bg_mcc, g32, 512, 512, 1024, 0);
    fcs_k<<<B * C, 256, 0, stream>>>(g32, fcs, HW, B, C);
    gemm_k<<<dim3(1, 16, 1), 256, 0, stream>>>(w_fc, fcs, b_fc, fc2t, 512, 512, 16);

    mf_k<float, us, 0, 0, us><<<dim3(8, 4, 16), 256, 0, stream>>>(
        wf_mcc, 0, 512, cnb, (long)C * HW, HW, bf_mcc, ffcb, nullptr, 512, 512, 1024, 0);

    mf_k<float, us, 0, 0, us><<<dim3(8, 2, 16), 256, 0, stream>>>(
        wc1, 0, 512, cnb, (long)C * HW, HW, bc1, t1, nullptr, 512, 256, 1024, 1);
    mf_k<float, us, 0, 0, us><<<dim3(8, 1, 16), 256, 0, stream>>>(
        wc2, 0, 256, t1, (long)256 * 1024, 1024, bc2, t2, nullptr, 256, 128, 1024, 1);
    mf_k<float, us, 0, 0, float><<<dim3(8, 1, 16), 256, 0, stream>>>(
        wc3, 0, 128, t2, (long)128 * 1024, 1024, bc3, fc_c, nullptr, 128, 32, 1024, 0);

    conv_mf_k<<<dim3(15, 4, 16), 256, 0, stream>>>(fs0b, (long)512 * 32 * 32, Wr1, bs1,
                                                   s1, (long)256 * 30 * 32, 512, 256, 32, 32, 30, 30, 32);
    conv_mf_k<<<dim3(14, 2, 16), 256, 0, stream>>>(s1, (long)256 * 30 * 32, Wr2, bs2,
                                                   s2, (long)128 * 28 * 28, 256, 128, 30, 32, 28, 28, 28);
    mf_k<float, us, 0, 0, float><<<dim3(7, 1, 16), 256, 0, stream>>>(
        ws3, 0, 128, s2, (long)128 * 784, 784, bs3, fs_c, nullptr, 128, 32, 784, 0);

    cov_k<<<B, 256, 0, stream>>>(fs_c, cov, 32, 784);
    g64_k<<<dim3(16, 1, 16), 256, 0, stream>>>(cov, 1024, 32, fc_c, (long)32 * 1024, 1024,
                                               nullptr, out32, 32, 32, 1024, 0);
    mf_k<float, float, 0, 0, us><<<dim3(8, 4, 16), 256, 0, stream>>>(
        w_unc, 0, 32, out32, (long)32 * 1024, 1024, b_unc, part2, nullptr, 32, 512, 1024, 0);

    mf_k<float, us, 0, 0, us><<<dim3(8, 4, 16), 256, 0, stream>>>(
        wf_san, 0, 512, cnb, (long)C * HW, HW, bf_san, Fsb, nullptr, 512, 512, 1024, 0);
    mf_k<float, us, 0, 0, us><<<dim3(8, 4, 16), 256, 0, stream>>>(
        wg_san, 0, 512, snb, (long)C * HW, HW, bg_san, Gsb, nullptr, 512, 512, 1024, 0);

    mf_k<us, us, 1, 0, float><<<dim3(8, 8, 16), 256, 0, stream>>>(
        Fsb, (long)C * HW, HW, Gsb, (long)C * HW, HW, nullptr, Sbuf, nullptr, 512, 1024, 1024, 0);
    softmax_k<<<B * HW, 256, 0, stream>>>(Sbuf, Pb);

    mf_k<float, float, 0, 0, us><<<dim3(8, 4, 16), 256, 0, stream>>>(
        wh_san, 0, 512, style, (long)C * HW, HW, bh_san, Hsb, nullptr, 512, 512, 1024, 0);
    mf_k<us, us, 0, 1, us><<<dim3(8, 4, 16), 256, 0, stream>>>(
        Hsb, (long)C * HW, HW, Pb, (long)HW * HW, HW, nullptr, part3, nullptr, 1024, 512, 1024, 0);

    fuse_k<<<(unsigned)((NE + 255) / 256), 256, 0, stream>>>(ffcb, fc2t, part2, part3, pbuf, B, C, HW);

    mf_k<float, us, 0, 0, float><<<dim3(8, 4, 16), 256, 0, stream>>>(
        w_out, 0, 512, pbuf, (long)C * HW, HW, b_out, (float*)d_out, content, 512, 512, 1024, 0);
}

// Round 8
// 1022.293 us; speedup vs baseline: 5.2655x; 1.2086x over previous
//
#include <hip/hip_runtime.h>
#include <hip/hip_bf16.h>
#include <math.h>

// Channel-major ([b][hw][c]) MFMA bf16 pipeline, fp32 accumulate.
// g-branch (ill-conditioned sum(g^2)/sum(g)) kept in full fp32 (VALU GEMM).

typedef __attribute__((ext_vector_type(8))) short short8;
typedef __attribute__((ext_vector_type(4))) float f32x4;
typedef unsigned short us;
#define MFMA16 __builtin_amdgcn_mfma_f32_16x16x32_bf16

__device__ inline float b2f(us b) { return __uint_as_float(((unsigned)b) << 16); }
__device__ inline us f2b(float f) {
    unsigned u = __float_as_uint(f);
    return (us)((u + 0x7FFFu + ((u >> 16) & 1u)) >> 16);
}

__device__ inline double blockReduceSumD(double v, double* sh) {
    int t = threadIdx.x;
    sh[t] = v; __syncthreads();
    for (int s = blockDim.x >> 1; s > 0; s >>= 1) {
        if (t < s) sh[t] += sh[t + s];
        __syncthreads();
    }
    double r = sh[0]; __syncthreads();
    return r;
}

// ---------- per-(b,c) spatial stats ----------
__global__ __launch_bounds__(256) void stats_k(const float* __restrict__ X,
                                               float* __restrict__ mean,
                                               float* __restrict__ inv, int HW) {
    __shared__ double sh[256];
    int bc = blockIdx.x;
    const float* x = X + (size_t)bc * HW;
    int t = threadIdx.x;
    float v[4];
    double s = 0.0;
    #pragma unroll
    for (int r = 0; r < 4; ++r) { v[r] = x[t + r * 256]; s += (double)v[r]; }
    double tot = blockReduceSumD(s, sh);
    double ss = 0.0;
    #pragma unroll
    for (int r = 0; r < 4; ++r) ss += (double)v[r] * (double)v[r];
    double tot2 = blockReduceSumD(ss, sh);
    if (t == 0) {
        double m = tot / HW;
        double var = (tot2 - tot * tot / HW) / (HW - 1);
        mean[bc] = (float)m;
        inv[bc] = (float)(1.0 / sqrt(var + 1e-5));
    }
}

// ---------- fp32 normalize in natural layout: sn32[b][c][hw] ----------
__global__ __launch_bounds__(256) void norm32_k(const float* __restrict__ X,
                                                const float* __restrict__ mean,
                                                const float* __restrict__ inv,
                                                float* __restrict__ Y, int HW) {
    int bc = blockIdx.x;
    float m = mean[bc], iv = inv[bc];
    const float* x = X + (size_t)bc * HW;
    float* y = Y + (size_t)bc * HW;
    int t = threadIdx.x;
    #pragma unroll
    for (int r = 0; r < 4; ++r) y[t + r * 256] = (x[t + r * 256] - m) * iv;
}

// ---------- transpose [b][C][HW] fp32 -> up to 3 bf16 [b][HW][C] outputs ----------
__global__ __launch_bounds__(256) void trn_k(const float* __restrict__ X,
                                             const float* __restrict__ mean,
                                             const float* __restrict__ inv,
                                             us* __restrict__ Yn, us* __restrict__ Yc,
                                             us* __restrict__ Yr, int C, int HW) {
    __shared__ us Ln[64 * 65];
    __shared__ us Lc[64 * 65];
    __shared__ us Lr[64 * 65];
    int bz = blockIdx.z, c0 = blockIdx.y * 64, h0 = blockIdx.x * 64;
    const float* Xb = X + (size_t)bz * C * HW;
    int t = threadIdx.x;
    int cl = t >> 3, h8 = (t & 7) * 8;
    #pragma unroll
    for (int half = 0; half < 2; ++half) {
        int c = cl + half * 32;
        int gc = c0 + c;
        float m = mean[bz * C + gc], iv = inv[bz * C + gc];
        const float4* s4 = (const float4*)&Xb[(size_t)gc * HW + h0 + h8];
        float4 f0 = s4[0], f1 = s4[1];
        float vv[8] = {f0.x, f0.y, f0.z, f0.w, f1.x, f1.y, f1.z, f1.w};
        #pragma unroll
        for (int i = 0; i < 8; ++i) {
            int li = c * 65 + h8 + i;
            if (Yn) Ln[li] = f2b((vv[i] - m) * iv);
            if (Yc) Lc[li] = f2b(vv[i] - m);
            if (Yr) Lr[li] = f2b(vv[i]);
        }
    }
    __syncthreads();
    int hl = t >> 3, c8 = (t & 7) * 8;
    #pragma unroll
    for (int half = 0; half < 2; ++half) {
        int hh = hl + half * 32;
        size_t off = ((size_t)bz * HW + h0 + hh) * (size_t)C + c0 + c8;
        us tmp[8];
        if (Yn) {
            #pragma unroll
            for (int i = 0; i < 8; ++i) tmp[i] = Ln[(c8 + i) * 65 + hh];
            *(uint4*)&Yn[off] = *(const uint4*)tmp;
        }
        if (Yc) {
            #pragma unroll
            for (int i = 0; i < 8; ++i) tmp[i] = Lc[(c8 + i) * 65 + hh];
            *(uint4*)&Yc[off] = *(const uint4*)tmp;
        }
        if (Yr) {
            #pragma unroll
            for (int i = 0; i < 8; ++i) tmp[i] = Lr[(c8 + i) * 65 + hh];
            *(uint4*)&Yr[off] = *(const uint4*)tmp;
        }
    }
}

// ---------- staging: 16 k-contiguous elems -> bf16 LDS ----------
template <typename TE>
__device__ inline void stage16(const TE* __restrict__ src, bool valid, us* dst) {
    us tmp[16];
    if (valid) {
        if constexpr (sizeof(TE) == 2) {
            uint4 a = ((const uint4*)src)[0], b = ((const uint4*)src)[1];
            *(uint4*)&tmp[0] = a; *(uint4*)&tmp[8] = b;
        } else {
            const float4* s4 = (const float4*)src;
            float4 f0 = s4[0], f1 = s4[1], f2 = s4[2], f3 = s4[3];
            float vv[16] = {f0.x, f0.y, f0.z, f0.w, f1.x, f1.y, f1.z, f1.w,
                            f2.x, f2.y, f2.z, f2.w, f3.x, f3.y, f3.z, f3.w};
            #pragma unroll
            for (int i = 0; i < 16; ++i) tmp[i] = f2b(vv[i]);
        }
    } else {
        #pragma unroll
        for (int i = 0; i < 16; ++i) tmp[i] = 0;
    }
    ((uint4*)dst)[0] = *(uint4*)&tmp[0];
    ((uint4*)dst)[1] = *(uint4*)&tmp[8];
}

// ---------- 128x128 MFMA GEMM, both operands k-contiguous ----------
// acc[m][n] = sum_k A[m][k] * B[n][k]
// OUTT=0: Y[b][m][n] row-major (+add_src fp32, scalar stores)
// OUTT=1: Y[b][n][m] (4 m-contig chunk stores)
template <typename TAel, typename TBel, typename TOUT, int OUTT>
__global__ __launch_bounds__(256) void mf2_k(const TAel* __restrict__ A, long astride, int lda,
                                             const TBel* __restrict__ B, long bstride, int ldb,
                                             const float* __restrict__ bias,
                                             TOUT* __restrict__ Y,
                                             const float* __restrict__ add_src,
                                             int K, int M, int N, int relu) {
    __shared__ us As[128][40];
    __shared__ us Bs[128][40];
    int bz = blockIdx.z;
    int mbase = blockIdx.y * 128, nbase = blockIdx.x * 128;
    const TAel* Ab = A + (size_t)bz * astride;
    const TBel* Bb = B + (size_t)bz * bstride;
    int t = threadIdx.x;
    int row = t & 127, kh = t >> 7;
    int wave = t >> 6, lane = t & 63, lm = lane & 15, q = lane >> 4;
    int mh = (wave >> 1) * 64, nh = (wave & 1) * 64;

    f32x4 acc[4][4];
    #pragma unroll
    for (int i = 0; i < 4; ++i)
        #pragma unroll
        for (int j = 0; j < 4; ++j) acc[i][j] = (f32x4){0.f, 0.f, 0.f, 0.f};

    for (int kb = 0; kb < K; kb += 32) {
        int gm = mbase + row;
        stage16(Ab + (size_t)gm * lda + kb + kh * 16, gm < M, &As[row][kh * 16]);
        int gn = nbase + row;
        stage16(Bb + (size_t)gn * ldb + kb + kh * 16, gn < N, &Bs[row][kh * 16]);
        __syncthreads();
        short8 af[4], bf[4];
        #pragma unroll
        for (int i = 0; i < 4; ++i) af[i] = *(const short8*)&As[mh + i * 16 + lm][q * 8];
        #pragma unroll
        for (int j = 0; j < 4; ++j) bf[j] = *(const short8*)&Bs[nh + j * 16 + lm][q * 8];
        #pragma unroll
        for (int i = 0; i < 4; ++i)
            #pragma unroll
            for (int j = 0; j < 4; ++j)
                acc[i][j] = MFMA16(af[i], bf[j], acc[i][j], 0, 0, 0);
        __syncthreads();
    }

    #pragma unroll
    for (int i = 0; i < 4; ++i) {
        int m0 = mbase + mh + i * 16 + q * 4;
        if (m0 >= M) continue;
        float bv[4];
        #pragma unroll
        for (int r = 0; r < 4; ++r) bv[r] = bias ? bias[m0 + r] : 0.f;
        #pragma unroll
        for (int j = 0; j < 4; ++j) {
            int n = nbase + nh + j * 16 + lm;
            if (n >= N) continue;
            float v[4];
            #pragma unroll
            for (int r = 0; r < 4; ++r) {
                float x = acc[i][j][r] + bv[r];
                if (relu) x = (x > 0.f) ? x : 0.f;
                v[r] = x;
            }
            if (OUTT == 1) {
                size_t off = ((size_t)bz * N + n) * (size_t)M + m0;
                if constexpr (sizeof(TOUT) == 2) {
                    us o4[4];
                    #pragma unroll
                    for (int r = 0; r < 4; ++r) o4[r] = f2b(v[r]);
                    *(uint2*)&Y[off] = *(const uint2*)o4;
                } else {
                    float4 f4 = make_float4(v[0], v[1], v[2], v[3]);
                    *(float4*)&Y[off] = f4;
                }
            } else {
                #pragma unroll
                for (int r = 0; r < 4; ++r) {
                    size_t off = ((size_t)bz * M + m0 + r) * (size_t)N + n;
                    float x = v[r];
                    if (add_src) x += add_src[off];
                    if constexpr (sizeof(TOUT) == 2) Y[off] = f2b(x);
                    else Y[off] = x;
                }
            }
        }
    }
}

// ---------- conv3x3 weight reorder: Wr[tap][o][c] bf16 ----------
__global__ __launch_bounds__(256) void reorder_w3_k(const float* __restrict__ W,
                                                    us* __restrict__ Wr, int O, int Cin) {
    int idx = blockIdx.x * 256 + threadIdx.x;
    int total = 9 * O * Cin;
    if (idx >= total) return;
    int tap = idx / (O * Cin);
    int rem = idx - tap * (O * Cin);
    int o = rem / Cin;
    int c = rem - o * Cin;
    Wr[idx] = f2b(W[((size_t)o * Cin + c) * 9 + tap]);
}

// ---------- MFMA conv3x3 VALID, channel-major in/out, relu fused ----------
__global__ __launch_bounds__(256) void conv_mf2_k(const us* __restrict__ X, long xbstride,
                                                  const us* __restrict__ Wr,
                                                  const float* __restrict__ bias,
                                                  us* __restrict__ Y, long ybstride,
                                                  int Cin, int O, int IH, int IW,
                                                  int OH, int OW) {
    __shared__ us patch[4 * 36 * 40];
    __shared__ us Ws[9 * 64 * 40];
    int bz = blockIdx.z;
    int obase = blockIdx.y * 64;
    int pyb = blockIdx.x * 2;
    const us* Xb = X + (size_t)bz * xbstride;
    int t = threadIdx.x;
    int wave = t >> 6, lane = t & 63, lm = lane & 15, q = lane >> 4;
    int mh = (wave >> 1) * 32, rw = wave & 1;

    f32x4 acc[2][2];
    #pragma unroll
    for (int i = 0; i < 2; ++i)
        #pragma unroll
        for (int j = 0; j < 2; ++j) acc[i][j] = (f32x4){0.f, 0.f, 0.f, 0.f};

    for (int cb = 0; cb < Cin; cb += 32) {
        __syncthreads();
        for (int i = t; i < 576; i += 256) {
            int p = i >> 2, q8 = (i & 3) * 8;
            int r = p / 36, x = p - r * 36;
            int gy = pyb + r;
            uint4 v = make_uint4(0u, 0u, 0u, 0u);
            if (x < IW && gy < IH)
                v = *(const uint4*)&Xb[((size_t)(gy * IW + x)) * Cin + cb + q8];
            *(uint4*)&patch[p * 40 + q8] = v;
        }
        for (int rowi = t; rowi < 576; rowi += 256) {
            int o_local = rowi & 63, tap = rowi >> 6;
            const us* src = Wr + ((size_t)tap * O + obase + o_local) * Cin + cb;
            uint4 a = ((const uint4*)src)[0], b = ((const uint4*)src)[1];
            uint4 c2 = ((const uint4*)src)[2], d = ((const uint4*)src)[3];
            us* dst = &Ws[rowi * 40];
            ((uint4*)dst)[0] = a; ((uint4*)dst)[1] = b;
            ((uint4*)dst)[2] = c2; ((uint4*)dst)[3] = d;
        }
        __syncthreads();
        #pragma unroll
        for (int tap = 0; tap < 9; ++tap) {
            int ky = tap / 3, kx = tap - ky * 3;
            short8 a0 = *(const short8*)&Ws[(tap * 64 + mh + lm) * 40 + q * 8];
            short8 a1 = *(const short8*)&Ws[(tap * 64 + mh + 16 + lm) * 40 + q * 8];
            int prow = (rw + ky) * 36;
            short8 b0 = *(const short8*)&patch[(prow + lm + kx) * 40 + q * 8];
            short8 b1 = *(const short8*)&patch[(prow + 16 + lm + kx) * 40 + q * 8];
            acc[0][0] = MFMA16(a0, b0, acc[0][0], 0, 0, 0);
            acc[0][1] = MFMA16(a0, b1, acc[0][1], 0, 0, 0);
            acc[1][0] = MFMA16(a1, b0, acc[1][0], 0, 0, 0);
            acc[1][1] = MFMA16(a1, b1, acc[1][1], 0, 0, 0);
        }
    }

    int py = pyb + rw;
    us* Yb = Y + (size_t)bz * ybstride;
    #pragma unroll
    for (int i = 0; i < 2; ++i) {
        int m0 = obase + mh + i * 16 + q * 4;
        #pragma unroll
        for (int j = 0; j < 2; ++j) {
            int px = j * 16 + lm;
            if (px >= OW) continue;
            us o4[4];
            #pragma unroll
            for (int r = 0; r < 4; ++r) {
                float v = acc[i][j][r] + bias[m0 + r];
                v = (v > 0.f) ? v : 0.f;
                o4[r] = f2b(v);
            }
            *(uint2*)&Yb[((size_t)(py * OW + px)) * O + m0] = *(const uint2*)o4;
        }
    }
}

// ---------- fp32 64x64 VALU GEMM (g-branch, accuracy-critical) ----------
__device__ inline float4 ld4_guard(const float* __restrict__ row, int n, int N) {
    if (n + 3 < N) return *(const float4*)(row + n);
    float4 v = make_float4(0.f, 0.f, 0.f, 0.f);
    if (n < N) v.x = row[n];
    if (n + 1 < N) v.y = row[n + 1];
    if (n + 2 < N) v.z = row[n + 2];
    return v;
}

__global__ __launch_bounds__(256) void g64_k(const float* __restrict__ P, long pstride, int lda,
                                             const float* __restrict__ Q, long qstride, int ldb,
                                             const float* __restrict__ bias,
                                             float* __restrict__ Y,
                                             int K, int M, int N, int relu) {
    int bb = blockIdx.z;
    int mbase = blockIdx.y * 64;
    int nbase = blockIdx.x * 64;
    const float* Pb = P + (size_t)bb * pstride;
    const float* Qb = Q + (size_t)bb * qstride;

    __shared__ float As[16][68];
    __shared__ float Bs[16][68];

    int t = threadIdx.x;
    int tx = t & 15, ty = t >> 4;
    float acc[4][4] = {{0}, {0}, {0}, {0}};

    for (int cb = 0; cb < K; cb += 16) {
        {
            int mm = t >> 2, k4 = (t & 3) * 4;
            int m = mbase + mm;
            float4 a = (m < M) ? *(const float4*)&Pb[(size_t)m * lda + cb + k4]
                               : make_float4(0.f, 0.f, 0.f, 0.f);
            As[k4 + 0][mm] = a.x; As[k4 + 1][mm] = a.y;
            As[k4 + 2][mm] = a.z; As[k4 + 3][mm] = a.w;
            int k = t >> 4, n4 = (t & 15) * 4;
            float4 b = ld4_guard(&Qb[(size_t)(cb + k) * ldb], nbase + n4, N);
            *(float4*)&Bs[k][n4] = b;
        }
        __syncthreads();
        #pragma unroll
        for (int k = 0; k < 16; ++k) {
            float4 a = *(const float4*)&As[k][ty * 4];
            float4 b = *(const float4*)&Bs[k][tx * 4];
            acc[0][0] += a.x * b.x; acc[0][1] += a.x * b.y; acc[0][2] += a.x * b.z; acc[0][3] += a.x * b.w;
            acc[1][0] += a.y * b.x; acc[1][1] += a.y * b.y; acc[1][2] += a.y * b.z; acc[1][3] += a.y * b.w;
            acc[2][0] += a.z * b.x; acc[2][1] += a.z * b.y; acc[2][2] += a.z * b.z; acc[2][3] += a.z * b.w;
            acc[3][0] += a.w * b.x; acc[3][1] += a.w * b.y; acc[3][2] += a.w * b.z; acc[3][3] += a.w * b.w;
        }
        __syncthreads();
    }
    #pragma unroll
    for (int i = 0; i < 4; ++i) {
        int m = mbase + ty * 4 + i;
        if (m >= M) continue;
        float bv = bias ? bias[m] : 0.f;
        size_t rowoff = ((size_t)bb * M + m) * N;
        #pragma unroll
        for (int j = 0; j < 4; ++j) {
            int n = nbase + tx * 4 + j;
            if (n >= N) continue;
            float v = acc[i][j] + bv;
            if (relu) v = (v > 0.f) ? v : 0.f;
            Y[rowoff + n] = v;
        }
    }
}

// ---------- legacy 32x32 fp32 GEMM (w_fc, N=16) ----------
__global__ __launch_bounds__(256) void gemm_k(const float* __restrict__ W,
                                              const float* __restrict__ X,
                                              const float* __restrict__ bias,
                                              float* __restrict__ Y,
                                              int C, int O, int N) {
    int obase = blockIdx.y * 32;
    __shared__ float As[32][33];
    __shared__ float Bs[32][33];
    int t = threadIdx.x;
    int tx = t & 15, ty = t >> 4;
    float acc00 = 0, acc01 = 0, acc10 = 0, acc11 = 0;
    for (int cb = 0; cb < C; cb += 32) {
        int k = t & 31, o0 = t >> 5;
        #pragma unroll
        for (int r = 0; r < 4; ++r) {
            int ol = o0 + r * 8;
            As[k][ol] = W[(size_t)(obase + ol) * C + cb + k];
        }
        int n0 = t & 31, k0 = t >> 5;
        #pragma unroll
        for (int r = 0; r < 4; ++r) {
            int k2 = k0 + r * 8;
            Bs[k2][n0] = (n0 < N) ? X[(size_t)(cb + k2) * N + n0] : 0.f;
        }
        __syncthreads();
        #pragma unroll
        for (int k2 = 0; k2 < 32; ++k2) {
            float a0 = As[k2][ty], a1 = As[k2][ty + 16];
            float b0 = Bs[k2][tx], b1 = Bs[k2][tx + 16];
            acc00 += a0 * b0; acc01 += a0 * b1;
            acc10 += a1 * b0; acc11 += a1 * b1;
        }
        __syncthreads();
    }
    float accs[2][2] = {{acc00, acc01}, {acc10, acc11}};
    #pragma unroll
    for (int i = 0; i < 2; ++i) {
        int o = obase + ty + i * 16;
        float bv = bias[o];
        #pragma unroll
        for (int j = 0; j < 2; ++j) {
            int n = tx + j * 16;
            if (n < N) Y[(size_t)o * N + n] = accs[i][j] + bv;
        }
    }
}

// ---------- FC_S reduction over g32 [b][o][hw] fp32 ----------
__global__ __launch_bounds__(256) void fcs_k(const float* __restrict__ g,
                                             float* __restrict__ fcs, int HW, int B, int C) {
    __shared__ double sh[256];
    int bc = blockIdx.x;
    int b = bc / C, c = bc - b * C;
    const float* x = g + (size_t)bc * HW;
    double s = 0.0, ss = 0.0;
    for (int i = threadIdx.x; i < HW; i += 256) {
        double v = (double)x[i];
        s += v; ss += v * v;
    }
    double ts = blockReduceSumD(s, sh);
    double tss = blockReduceSumD(ss, sh);
    if (threadIdx.x == 0) fcs[(size_t)c * B + b] = (float)(tss / ts);
}

// ---------- softmax fp32 -> bf16 P ----------
__global__ __launch_bounds__(256) void softmax_k(const float* __restrict__ S,
                                                 us* __restrict__ P) {
    __shared__ float sh[256];
    size_t row = blockIdx.x;
    const float* r = S + row * 1024;
    us* po = P + row * 1024;
    int t = threadIdx.x;
    float v[4];
    float m = -INFINITY;
    #pragma unroll
    for (int i = 0; i < 4; ++i) { v[i] = r[t + i * 256]; m = fmaxf(m, v[i]); }
    sh[t] = m; __syncthreads();
    for (int s = 128; s > 0; s >>= 1) { if (t < s) sh[t] = fmaxf(sh[t], sh[t + s]); __syncthreads(); }
    m = sh[0]; __syncthreads();
    float sum = 0;
    #pragma unroll
    for (int i = 0; i < 4; ++i) { v[i] = expf(v[i] - m); sum += v[i]; }
    sh[t] = sum; __syncthreads();
    for (int s = 128; s > 0; s >>= 1) { if (t < s) sh[t] += sh[t + s]; __syncthreads(); }
    float inv = 1.f / sh[0]; __syncthreads();
    #pragma unroll
    for (int i = 0; i < 4; ++i) po[t + i * 256] = f2b(v[i] * inv);
}

// ---------- covariance from fs [b][784][32] fp32 ----------
__global__ __launch_bounds__(256) void cov2_k(const float* __restrict__ fs,
                                              float* __restrict__ cov, int Cd, int M) {
    __shared__ float Ls[196 * 36];
    int bb = blockIdx.x;
    int t = threadIdx.x;
    const float* p = fs + (size_t)bb * M * Cd;
    int c = t >> 3, d0 = (t & 7) * 4;
    float a0 = 0.f, a1 = 0.f, a2 = 0.f, a3 = 0.f;
    for (int ch = 0; ch < 4; ++ch) {
        __syncthreads();
        for (int i = t; i < 1568; i += 256) {
            int rowi = i >> 3, c4 = (i & 7) * 4;
            float4 v = *(const float4*)&p[(size_t)(ch * 196 + rowi) * Cd + c4];
            *(float4*)&Ls[rowi * 36 + c4] = v;
        }
        __syncthreads();
        for (int i = 0; i < 196; ++i) {
            float a = Ls[i * 36 + c];
            a0 += a * Ls[i * 36 + d0 + 0];
            a1 += a * Ls[i * 36 + d0 + 1];
            a2 += a * Ls[i * 36 + d0 + 2];
            a3 += a * Ls[i * 36 + d0 + 3];
        }
    }
    float invM = 1.f / (float)M;
    size_t base = ((size_t)bb * Cd + c) * Cd + d0;
    cov[base + 0] = a0 * invM;
    cov[base + 1] = a1 * invM;
    cov[base + 2] = a2 * invM;
    cov[base + 3] = a3 * invM;
}

// ---------- fused epilogue over [b][token][c] ----------
__global__ __launch_bounds__(256) void fuse_k(const us* __restrict__ ffc,
                                              const float* __restrict__ fc2t,
                                              const us* __restrict__ p2,
                                              const us* __restrict__ p3,
                                              us* __restrict__ out, int B, int C, int HW) {
    size_t idx = (size_t)blockIdx.x * 256 + threadIdx.x;
    size_t total = (size_t)B * C * HW;
    if (idx >= total) return;
    int c = (int)(idx & (size_t)(C - 1));
    int b = (int)(idx / ((size_t)C * HW));
    float part1 = b2f(ffc[idx]) * fc2t[(size_t)c * B + b];
    float v = part1 * b2f(p2[idx]) * b2f(p3[idx]);
    v = (v > 0.f) ? v : 0.f;
    out[idx] = f2b(cbrtf(v));
}

// ---------- launch ----------
extern "C" void kernel_launch(void* const* d_in, const int* in_sizes, int n_in,
                              void* d_out, int out_size, void* d_ws, size_t ws_size,
                              hipStream_t stream) {
    typedef const float* fp;
    fp content = (fp)d_in[0];
    fp style   = (fp)d_in[1];
    fp wf_san = (fp)d_in[2],  bf_san = (fp)d_in[3];
    fp wg_san = (fp)d_in[4],  bg_san = (fp)d_in[5];
    fp wh_san = (fp)d_in[6],  bh_san = (fp)d_in[7];
    fp wf_mcc = (fp)d_in[8],  bf_mcc = (fp)d_in[9];
    fp wg_mcc = (fp)d_in[10], bg_mcc = (fp)d_in[11];
    fp w_fc   = (fp)d_in[12], b_fc   = (fp)d_in[13];
    fp w_out  = (fp)d_in[14], b_out  = (fp)d_in[15];
    fp wc1 = (fp)d_in[16], bc1 = (fp)d_in[17];
    fp wc2 = (fp)d_in[18], bc2 = (fp)d_in[19];
    fp wc3 = (fp)d_in[20], bc3 = (fp)d_in[21];
    fp ws1 = (fp)d_in[22], bs1 = (fp)d_in[23];
    fp ws2 = (fp)d_in[24], bs2 = (fp)d_in[25];
    fp ws3 = (fp)d_in[26], bs3 = (fp)d_in[27];
    fp w_unc = (fp)d_in[28], b_unc = (fp)d_in[29];

    const int B = 16, C = 512, HW = 1024;
    const size_t NE = (size_t)B * C * HW;       // 8388608
    const long TOK = (long)C * HW;              // 524288 per-batch elems
    char* base = (char*)d_ws;
    const size_t SL = 16777216;                 // 16 MiB slot

    // slots (time-multiplexed):
    float* sn32  = (float*)(base + 0 * SL);     // S0-S1 fp32 sn [b][c][hw], dead after g-GEMM
    float* Sbuf  = (float*)(base + 0 * SL);     // S0-S3 logits (step 8+)
    us* fs0T  = (us*)(base + 3 * SL);           // S3: centered style [b][hw][c], dead after conv1
    us* cnT   = (us*)(base + 4 * SL);           // S4 -> P (low)
    us* snT   = (us*)(base + 5 * SL);           // S5 -> P (high)
    us* Pb    = (us*)(base + 4 * SL);           // 32 MiB over S4+S5
    us* styleT = (us*)(base + 6 * SL);          // S6
    us* ffcb  = (us*)(base + 7 * SL);           // S7 (pbuf in place)
    us* Fsb   = (us*)(base + 8 * SL);           // S8 -> part3
    us* Gsb   = (us*)(base + 9 * SL);           // S9 -> Hco
    us* part2 = (us*)(base + 10 * SL);          // S10
    float* g32 = (float*)(base + 11 * SL);      // S11-S12 fp32 g, dead after fcs
    us* t1 = (us*)(base + 11 * SL);
    us* t2 = (us*)(base + 11 * SL + 8388608);
    us* s1 = (us*)(base + 12 * SL);
    us* s2 = (us*)(base + 12 * SL + 7372800);
    us* part3 = Fsb;
    us* Hco   = Gsb;
    us* pbuf  = ffcb;

    char* misc = base + 13 * SL;
    us* Wr1 = (us*)(misc);
    us* Wr2 = (us*)(misc + 2359296);
    float* fc_c  = (float*)(misc + 2949120);
    float* fs_c  = (float*)(misc + 5046272);
    float* out32 = (float*)(misc + 6651904);
    float* fcs   = (float*)(misc + 8749056);
    float* fc2t  = (float*)(misc + 8781824);
    float* cov   = (float*)(misc + 8814592);
    float* meanC = (float*)(misc + 8880128);
    float* invC  = (float*)(misc + 8912896);
    float* meanS = (float*)(misc + 8945664);
    float* invS  = (float*)(misc + 8978432);

    // 0: conv weights -> bf16 [tap][o][c]
    reorder_w3_k<<<4608, 256, 0, stream>>>(ws1, Wr1, 256, 512);
    reorder_w3_k<<<1152, 256, 0, stream>>>(ws2, Wr2, 128, 256);

    // 1: stats; fp32 sn32 (natural layout); bf16 transposes
    stats_k<<<B * C, 256, 0, stream>>>(content, meanC, invC, HW);
    stats_k<<<B * C, 256, 0, stream>>>(style, meanS, invS, HW);
    norm32_k<<<B * C, 256, 0, stream>>>(style, meanS, invS, sn32, HW);
    trn_k<<<dim3(16, 8, 16), 256, 0, stream>>>(content, meanC, invC, cnT, nullptr, nullptr, C, HW);
    trn_k<<<dim3(16, 8, 16), 256, 0, stream>>>(style, meanS, invS, snT, fs0T, styleT, C, HW);

    // 2: g = wg_mcc . sn (FULL fp32 — ill-conditioned FC_S branch); stats; fc2t
    g64_k<<<dim3(16, 8, 16), 256, 0, stream>>>(wg_mcc, 0, 512, sn32, TOK, HW,
                                               bg_mcc, g32, 512, 512, 1024, 0);
    fcs_k<<<B * C, 256, 0, stream>>>(g32, fcs, HW, B, C);
    gemm_k<<<dim3(1, 16, 1), 256, 0, stream>>>(w_fc, fcs, b_fc, fc2t, 512, 512, 16);

    // 3: ffc = wf_mcc . cn -> [b][hw][512] bf16
    mf2_k<float, us, us, 1><<<dim3(8, 4, 16), 256, 0, stream>>>(
        wf_mcc, 0, 512, cnT, TOK, 512, bf_mcc, ffcb, nullptr, 512, 512, 1024, 0);

    // 4: fc chain (relu)
    mf2_k<float, us, us, 1><<<dim3(8, 2, 16), 256, 0, stream>>>(
        wc1, 0, 512, cnT, TOK, 512, bc1, t1, nullptr, 512, 256, 1024, 1);
    mf2_k<float, us, us, 1><<<dim3(8, 1, 16), 256, 0, stream>>>(
        wc2, 0, 256, t1, (long)1024 * 256, 256, bc2, t2, nullptr, 256, 128, 1024, 1);
    mf2_k<float, us, float, 1><<<dim3(8, 1, 16), 256, 0, stream>>>(
        wc3, 0, 128, t2, (long)1024 * 128, 128, bc3, fc_c, nullptr, 128, 32, 1024, 0);

    // 5: conv3x3 chain (channel-major)
    conv_mf2_k<<<dim3(15, 4, 16), 256, 0, stream>>>(fs0T, TOK, Wr1, bs1,
                                                    s1, (long)900 * 256, 512, 256, 32, 32, 30, 30);
    conv_mf2_k<<<dim3(14, 2, 16), 256, 0, stream>>>(s1, (long)900 * 256, Wr2, bs2,
                                                    s2, (long)784 * 128, 256, 128, 30, 30, 28, 28);
    mf2_k<float, us, float, 1><<<dim3(7, 1, 16), 256, 0, stream>>>(
        ws3, 0, 128, s2, (long)784 * 128, 128, bs3, fs_c, nullptr, 128, 32, 784, 0);

    // 6: cov, out32, part2
    cov2_k<<<B, 256, 0, stream>>>(fs_c, cov, 32, 784);
    mf2_k<float, float, float, 1><<<dim3(8, 1, 16), 256, 0, stream>>>(
        cov, 1024, 32, fc_c, (long)1024 * 32, 32, nullptr, out32, nullptr, 32, 32, 1024, 0);
    mf2_k<float, float, us, 1><<<dim3(8, 4, 16), 256, 0, stream>>>(
        w_unc, 0, 32, out32, (long)1024 * 32, 32, b_unc, part2, nullptr, 32, 512, 1024, 0);

    // 7: SANet F/G projections (last uses of cnT, snT)
    mf2_k<float, us, us, 1><<<dim3(8, 4, 16), 256, 0, stream>>>(
        wf_san, 0, 512, cnT, TOK, 512, bf_san, Fsb, nullptr, 512, 512, 1024, 0);
    mf2_k<float, us, us, 1><<<dim3(8, 4, 16), 256, 0, stream>>>(
        wg_san, 0, 512, snT, TOK, 512, bg_san, Gsb, nullptr, 512, 512, 1024, 0);

    // 8: logits S[i][j] (fp32, S0-S3) + softmax -> P (S4-S5)
    mf2_k<us, us, float, 0><<<dim3(8, 8, 16), 256, 0, stream>>>(
        Fsb, TOK, 512, Gsb, TOK, 512, nullptr, Sbuf, nullptr, 512, 1024, 1024, 0);
    softmax_k<<<B * HW, 256, 0, stream>>>(Sbuf, Pb);

    // 9: H = wh_san . style -> [b][o][hw] bf16 (into S9)
    mf2_k<float, us, us, 0><<<dim3(8, 4, 16), 256, 0, stream>>>(
        wh_san, 0, 512, styleT, TOK, 512, bh_san, Hco, nullptr, 512, 512, 1024, 0);

    // 10: part3[i][c] = sum_j P[i][j] H[c][j]  (into S8)
    mf2_k<us, us, us, 0><<<dim3(4, 8, 16), 256, 0, stream>>>(
        Pb, (long)1024 * 1024, 1024, Hco, TOK, 1024, nullptr, part3, nullptr, 1024, 1024, 512, 0);

    // 11: p = cbrt(relu(part1*part2*part3)) in place
    fuse_k<<<(unsigned)((NE + 255) / 256), 256, 0, stream>>>(ffcb, fc2t, part2, part3, pbuf, B, C, HW);

    // 12: out = w_out . p + b_out + content -> d_out fp32 [b][o][hw]
    mf2_k<float, us, float, 0><<<dim3(8, 4, 16), 256, 0, stream>>>(
        w_out, 0, 512, pbuf, TOK, 512, b_out, (float*)d_out, content, 512, 512, 1024, 0);
}